// Round 2
// baseline (52628.607 us; speedup 1.0000x reference)
//
#include <hip/hip_runtime.h>
#include <math.h>

// ---------------- constants ----------------
#define NTOK 30464    // 448*68
#define NEMB 28672    // 448*64
#define NCH 8         // chunks
#define SCH 56        // series per chunk (448/8)
#define RCH 3808      // token rows per chunk (56*68)
#define FLAG_GELU 1
#define FLAG_RESID 2

// ---------------- helpers ----------------
__device__ __forceinline__ float block_reduce_sum(float v, float* scratch) {
  __syncthreads();
  #pragma unroll
  for (int o = 32; o; o >>= 1) v += __shfl_xor(v, o, 64);
  int wid = threadIdx.x >> 6, lane = threadIdx.x & 63;
  if (lane == 0) scratch[wid] = v;
  __syncthreads();
  if (threadIdx.x == 0) {
    float s = 0.f;
    int nw = (blockDim.x + 63) >> 6;
    for (int i = 0; i < nw; i++) s += scratch[i];
    scratch[0] = s;
  }
  __syncthreads();
  return scratch[0];
}

__device__ __forceinline__ float gelu_f(float x) {
  float x3 = x * x * x;
  return 0.5f * x * (1.0f + tanhf(0.7978845608028654f * (x + 0.044715f * x3)));
}

// ---------------- RevIN: means/stdev + transpose to (448,512) ----------------
__global__ __launch_bounds__(256) void revin_kernel(const float* __restrict__ x,
    float* __restrict__ xr, float* __restrict__ means, float* __restrict__ stdev) {
  int bm = blockIdx.x;            // b*7+m
  int b = bm / 7, m = bm % 7;
  int tid = threadIdx.x;
  __shared__ float red[8];
  float v0 = x[(size_t)b * 3584 + (size_t)tid * 7 + m];
  float v1 = x[(size_t)b * 3584 + (size_t)(tid + 256) * 7 + m];
  float s  = block_reduce_sum(v0 + v1, red);
  float ss = block_reduce_sum(v0 * v0 + v1 * v1, red);
  float mean = s * (1.0f / 512.0f);
  float var  = ss * (1.0f / 512.0f) - mean * mean;
  float sd = sqrtf(var + 1e-5f);
  if (tid == 0) { means[bm] = mean; stdev[bm] = sd; }
  float inv = 1.0f / sd;
  xr[(size_t)bm * 512 + tid]       = (v0 - mean) * inv;
  xr[(size_t)bm * 512 + tid + 256] = (v1 - mean) * inv;
}

// ---------------- decompose: trend / seasonal / resid ----------------
__global__ __launch_bounds__(256) void decompose_kernel(const float* __restrict__ xr,
    float* __restrict__ dec) {
  int n = blockIdx.x, tid = threadIdx.x;
  __shared__ float xv[512];
  __shared__ float tr[512];
  __shared__ float sumS[24];
  for (int l = tid; l < 512; l += 256) xv[l] = xr[(size_t)n * 512 + l];
  if (tid < 24) sumS[tid] = 0.f;
  __syncthreads();
  for (int l = tid; l < 512; l += 256) {
    int t0 = l - 12; t0 = t0 < 0 ? 0 : (t0 > 488 ? 488 : t0);
    float s = 0.f;
    #pragma unroll
    for (int j = 0; j < 24; j++) s += xv[t0 + j];
    float t = s * (1.0f / 24.0f);
    tr[l] = t;
    atomicAdd(&sumS[l % 24], xv[l] - t);
  }
  __syncthreads();
  if (tid < 24) sumS[tid] *= (tid < 8) ? (1.0f / 22.0f) : (1.0f / 21.0f);
  __syncthreads();
  float* dp = dec + (size_t)n * 1536;
  for (int l = tid; l < 512; l += 256) {
    float t = tr[l], se = sumS[l % 24];
    dp[l] = t;
    dp[512 + l] = se;
    dp[1024 + l] = xv[l] - t - se;
  }
}

// ---------------- patch + embed -> h rows 4..67 (NO wpe yet) ----------------
__global__ __launch_bounds__(256) void embed_kernel(const float* __restrict__ dec,
    const float* __restrict__ in_w, const float* __restrict__ in_b, float* __restrict__ h) {
  int np = blockIdx.x;            // n*64 + p
  int n = np >> 6, p = np & 63;
  int tid = threadIdx.x;
  __shared__ float tok[48];
  if (tid < 48) {
    int c = tid >> 4, j = tid & 15;
    int l = p * 8 + j; if (l > 511) l = 511;      // repeat-pad last value
    tok[tid] = dec[(size_t)n * 1536 + (size_t)c * 512 + l];
  }
  __syncthreads();
  float* outp = h + ((size_t)n * 68 + 4 + p) * 768;
  #pragma unroll
  for (int i = 0; i < 3; i++) {
    int d = tid + i * 256;
    float acc = in_b[d];
    #pragma unroll
    for (int k = 0; k < 48; k++) acc += tok[k] * in_w[(size_t)k * 768 + d];
    outp[d] = acc;
  }
}

// ---------------- key normalization (f32 keys + f64 inv-norms) ----------------
__global__ __launch_bounds__(256) void keyn_kernel(const float* __restrict__ pkey,
    float* __restrict__ keyn, double* __restrict__ kinv) {
  int k = blockIdx.x, tid = threadIdx.x;
  __shared__ double redd[4];
  float v[3];
  double ss = 0.0;
  #pragma unroll
  for (int i = 0; i < 3; i++) {
    v[i] = pkey[(size_t)k * 768 + tid + i * 256];
    ss += (double)v[i] * (double)v[i];
  }
  #pragma unroll
  for (int o = 32; o; o >>= 1) ss += __shfl_xor(ss, o, 64);
  int wid = tid >> 6, lane = tid & 63;
  if (lane == 0) redd[wid] = ss;
  __syncthreads();
  if (tid == 0) redd[0] = redd[0] + redd[1] + redd[2] + redd[3];
  __syncthreads();
  ss = redd[0];
  double inv = 1.0 / sqrt(ss > 1e-12 ? ss : 1e-12);
  #pragma unroll
  for (int i = 0; i < 3; i++)
    keyn[(size_t)k * 768 + tid + i * 256] = (float)((double)v[i] * inv);
  if (tid == 0) kinv[k] = inv;
}

// ---------------- xq = l2n(mean_p h[n, 4..67]) ----------------
__global__ __launch_bounds__(256) void xq_kernel(const float* __restrict__ h,
    float* __restrict__ xq) {
  int n = blockIdx.x, tid = threadIdx.x;
  __shared__ float red[8];
  float vals[3];
  float ssl = 0.f;
  #pragma unroll
  for (int i = 0; i < 3; i++) {
    int d = tid + i * 256;
    const float* p = h + ((size_t)n * 68 + 4) * 768 + d;
    float s = 0.f;
    for (int pc = 0; pc < 64; pc++) s += p[(size_t)pc * 768];
    s *= (1.0f / 64.0f);
    vals[i] = s; ssl += s * s;
  }
  float ss = block_reduce_sum(ssl, red);
  float inv = rsqrtf(fmaxf(ss, 1e-12f));
  #pragma unroll
  for (int i = 0; i < 3; i++)
    xq[(size_t)n * 768 + tid + i * 256] = vals[i] * inv;
}

__global__ void zero_kernel(float* p) {
  if (threadIdx.x == 0 && blockIdx.x == 0) p[0] = 0.f;
}

// ---------------- sim (f64) + top-4 + prompt rows of h + reduce_sim ----------------
__global__ __launch_bounds__(256) void simtopk_kernel(
    const float* __restrict__ xq, const float* __restrict__ pkey,
    const double* __restrict__ kinv, const float* __restrict__ keyn,
    const float* __restrict__ wpe, float* __restrict__ h, float* __restrict__ rs_out) {
  int n = blockIdx.x, tid = threadIdx.x;
  __shared__ __align__(16) float xqv[768];
  __shared__ double simd_s[1000];
  __shared__ int idxs[4];
  __shared__ double redv[4];
  __shared__ int redi[4];
  __shared__ float red2[8];
  #pragma unroll
  for (int i = 0; i < 3; i++) xqv[tid + i * 256] = xq[(size_t)n * 768 + tid + i * 256];
  __syncthreads();
  for (int k = tid; k < 1000; k += 256) {
    const float* kp = pkey + (size_t)k * 768;
    double acc = 0.0;
    for (int d = 0; d < 768; d++) acc += (double)kp[d] * (double)xqv[d];
    simd_s[k] = acc * kinv[k];
  }
  __syncthreads();
  int lane = tid & 63, wid = tid >> 6;
  for (int r = 0; r < 4; r++) {
    double bv = -1e300; int bi = 0x7fffffff;
    for (int k = tid; k < 1000; k += 256) {
      double v = simd_s[k];
      if (v > bv || (v == bv && k < bi)) { bv = v; bi = k; }
    }
    #pragma unroll
    for (int off = 32; off; off >>= 1) {
      double ov = __shfl_xor(bv, off, 64);
      int oi = __shfl_xor(bi, off, 64);
      if (ov > bv || (ov == bv && oi < bi)) { bv = ov; bi = oi; }
    }
    if (lane == 0) { redv[wid] = bv; redi[wid] = bi; }
    __syncthreads();
    if (tid == 0) {
      double fv = redv[0]; int fi = redi[0];
      for (int w = 1; w < 4; w++)
        if (redv[w] > fv || (redv[w] == fv && redi[w] < fi)) { fv = redv[w]; fi = redi[w]; }
      idxs[r] = fi; simd_s[fi] = -1e300;
    }
    __syncthreads();
  }
  float part = 0.f;
  for (int r = 0; r < 4; r++) {
    int ki = idxs[r];
    const float* kp = keyn + (size_t)ki * 768;
    const float* wp = wpe + (size_t)r * 768;
    float* hp = h + ((size_t)n * 68 + r) * 768;
    #pragma unroll
    for (int i = 0; i < 3; i++) {
      int d = tid + i * 256;
      float kv = kp[d];
      hp[d] = kv + wp[d];
      part += kv * xqv[d];
    }
  }
  part = block_reduce_sum(part, red2);
  if (tid == 0) atomicAdd(rs_out, part * (1.0f / 448.0f));
}

// ---------------- h rows 4..67 += wpe ----------------
__global__ __launch_bounds__(256) void addwpe_kernel(const float* __restrict__ wpe,
    float* __restrict__ h) {
  int np = blockIdx.x;
  int n = np >> 6, p = np & 63;
  int tid = threadIdx.x;
  const float* wp = wpe + (size_t)(4 + p) * 768;
  float* hp = h + ((size_t)n * 68 + 4 + p) * 768;
  #pragma unroll
  for (int i = 0; i < 3; i++) { int d = tid + i * 256; hp[d] += wp[d]; }
}

// ---------------- LayerNorm over 768 ----------------
__global__ __launch_bounds__(256) void ln_kernel(const float* __restrict__ src,
    float* __restrict__ dst, const float* __restrict__ g, const float* __restrict__ b) {
  size_t row = blockIdx.x;
  const float* xp = src + row * 768;
  float* yp = dst + row * 768;
  int tid = threadIdx.x;
  float v0 = xp[tid], v1 = xp[tid + 256], v2 = xp[tid + 512];
  __shared__ float red[8];
  float s  = block_reduce_sum(v0 + v1 + v2, red);
  float ss = block_reduce_sum(v0 * v0 + v1 * v1 + v2 * v2, red);
  float mean = s * (1.0f / 768.0f);
  float var  = ss * (1.0f / 768.0f) - mean * mean;
  float rs = rsqrtf(var + 1e-5f);
  yp[tid]       = (v0 - mean) * rs * g[tid]       + b[tid];
  yp[tid + 256] = (v1 - mean) * rs * g[tid + 256] + b[tid + 256];
  yp[tid + 512] = (v2 - mean) * rs * g[tid + 512] + b[tid + 512];
}

// ---------------- generic fp32 GEMM: C = A(MxK) @ W(KxN) + bias, fused gelu/resid ----------------
// 128x64 tile, 256 threads, 8x4 per-thread microtile, BK=16.
__global__ __launch_bounds__(256) void sgemm_kernel(
    const float* __restrict__ A, const float* __restrict__ W,
    const float* __restrict__ bias, float* __restrict__ C,
    int M, int N, int K, int flags) {
  __shared__ float As[16][132];   // [k][m]
  __shared__ float Bs[16][64];    // [k][n]
  const int tid = threadIdx.x;
  const int row0 = blockIdx.y * 128, col0 = blockIdx.x * 64;
  const int tx = tid & 15, ty = tid >> 4;
  float acc[8][4] = {};
  const int am0 = tid >> 2;           // 0..63 (then +64)
  const int ak0 = (tid & 3) * 4;      // k within tile, float4
  const int bn = (tid & 15) * 4, bk = tid >> 4;
  for (int kb = 0; kb < K; kb += 16) {
    __syncthreads();
    #pragma unroll
    for (int i = 0; i < 2; i++) {
      int m = am0 + i * 64;
      int grow = row0 + m;
      float4 v = make_float4(0.f, 0.f, 0.f, 0.f);
      if (grow < M) v = *(const float4*)(A + (size_t)grow * K + kb + ak0);
      As[ak0 + 0][m] = v.x; As[ak0 + 1][m] = v.y;
      As[ak0 + 2][m] = v.z; As[ak0 + 3][m] = v.w;
    }
    {
      int gcol = col0 + bn;
      float4 v = make_float4(0.f, 0.f, 0.f, 0.f);
      if (gcol < N) v = *(const float4*)(W + (size_t)(kb + bk) * N + gcol);
      *(float4*)&Bs[bk][bn] = v;
    }
    __syncthreads();
    #pragma unroll
    for (int k = 0; k < 16; k++) {
      float4 a0 = *(const float4*)&As[k][ty * 8];
      float4 a1 = *(const float4*)&As[k][ty * 8 + 4];
      float4 bb = *(const float4*)&Bs[k][tx * 4];
      float av[8] = {a0.x, a0.y, a0.z, a0.w, a1.x, a1.y, a1.z, a1.w};
      float bv[4] = {bb.x, bb.y, bb.z, bb.w};
      #pragma unroll
      for (int i = 0; i < 8; i++)
        #pragma unroll
        for (int j = 0; j < 4; j++)
          acc[i][j] += av[i] * bv[j];
    }
  }
  #pragma unroll
  for (int i = 0; i < 8; i++) {
    int grow = row0 + ty * 8 + i;
    if (grow >= M) continue;
    float* crow = C + (size_t)grow * N;
    #pragma unroll
    for (int j = 0; j < 4; j++) {
      int gcol = col0 + tx * 4 + j;
      if (gcol >= N) continue;
      float v = acc[i][j] + bias[gcol];
      if (flags & FLAG_GELU) v = gelu_f(v);
      if (flags & FLAG_RESID) v += crow[gcol];
      crow[gcol] = v;
    }
  }
}

// ---------------- attention over one chunk: blockIdx = nl*12 + head ----------------
__global__ __launch_bounds__(256) void attn_kernel(const float* __restrict__ qkvc,
    float* __restrict__ obase) {
  __shared__ float qs[68][65];
  __shared__ float ks[68][65];
  __shared__ float vs[68][65];
  int nh = blockIdx.x;
  int nl = nh / 12, hh = nh % 12;     // local series index in chunk
  int tid = threadIdx.x;
  const float* base = qkvc + (size_t)nl * 68 * 2304 + hh * 64;
  for (int idx = tid; idx < 68 * 64; idx += 256) {
    int t = idx >> 6, d = idx & 63;
    const float* rp = base + (size_t)t * 2304 + d;
    qs[t][d] = rp[0];
    ks[t][d] = rp[768];
    vs[t][d] = rp[1536];
  }
  __syncthreads();
  int wid = tid >> 6, lane = tid & 63;
  for (int qt = wid; qt < 68; qt += 4) {
    float s1 = -1e30f, s2 = -1e30f;
    if (lane <= qt) {
      float acc = 0.f;
      #pragma unroll
      for (int d = 0; d < 64; d++) acc += qs[qt][d] * ks[lane][d];
      s1 = acc * 0.125f;
    }
    if (lane < 4 && 64 + lane <= qt) {
      float acc = 0.f;
      #pragma unroll
      for (int d = 0; d < 64; d++) acc += qs[qt][d] * ks[64 + lane][d];
      s2 = acc * 0.125f;
    }
    float mx = fmaxf(s1, s2);
    #pragma unroll
    for (int off = 32; off; off >>= 1) mx = fmaxf(mx, __shfl_xor(mx, off, 64));
    float e1 = (lane <= qt) ? __expf(s1 - mx) : 0.f;
    float e2 = (lane < 4 && 64 + lane <= qt) ? __expf(s2 - mx) : 0.f;
    float sum = e1 + e2;
    #pragma unroll
    for (int off = 32; off; off >>= 1) sum += __shfl_xor(sum, off, 64);
    float inv = 1.0f / sum;
    float a1 = e1 * inv, a2 = e2 * inv;
    float oacc = 0.f;
    int d = lane;
    int kmax1 = qt < 63 ? qt : 63;
    for (int kt = 0; kt <= kmax1; kt++) oacc += __shfl(a1, kt, 64) * vs[kt][d];
    for (int kt = 64; kt <= qt; kt++)   oacc += __shfl(a2, kt - 64, 64) * vs[kt][d];
    obase[((size_t)nl * 68 + qt) * 768 + hh * 64 + d] = oacc;
  }
}

// ---------------- final combine: sum 3 components, de-normalize ----------------
__global__ void combine_kernel(const float* __restrict__ of, const float* __restrict__ stdev,
    const float* __restrict__ means, float* __restrict__ out) {
  int bm = blockIdx.x;
  int b = bm / 7, m = bm % 7;
  int j = threadIdx.x;
  if (j < 96) {
    float s = of[(size_t)(bm * 3 + 0) * 96 + j]
            + of[(size_t)(bm * 3 + 1) * 96 + j]
            + of[(size_t)(bm * 3 + 2) * 96 + j];
    out[(size_t)b * 672 + (size_t)j * 7 + m] = s * stdev[bm] + means[bm];
  }
}

// ---------------- launcher ----------------
extern "C" void kernel_launch(void* const* d_in, const int* in_sizes, int n_in,
                              void* d_out, int out_size, void* d_ws, size_t ws_size,
                              hipStream_t stream) {
  (void)in_sizes; (void)n_in; (void)out_size; (void)ws_size;
  const float* x     = (const float*)d_in[0];
  const float* in_w  = (const float*)d_in[2];
  const float* in_b  = (const float*)d_in[3];
  const float* pkey  = (const float*)d_in[4];
  const float* wpe   = (const float*)d_in[5];
  const float* ln1_g = (const float*)d_in[6];
  const float* ln1_b = (const float*)d_in[7];
  const float* qkv_w = (const float*)d_in[8];
  const float* qkv_b = (const float*)d_in[9];
  const float* aw    = (const float*)d_in[10];
  const float* ab    = (const float*)d_in[11];
  const float* ln2_g = (const float*)d_in[12];
  const float* ln2_b = (const float*)d_in[13];
  const float* fc_w  = (const float*)d_in[14];
  const float* fc_b  = (const float*)d_in[15];
  const float* mp_w  = (const float*)d_in[16];
  const float* mp_b  = (const float*)d_in[17];
  const float* lnf_g = (const float*)d_in[18];
  const float* lnf_b = (const float*)d_in[19];
  const float* out_w = (const float*)d_in[20];
  const float* out_b = (const float*)d_in[21];
  float* out = (float*)d_out;
  float* ws  = (float*)d_ws;

  // workspace layout (floats) — peak ~243 MB
  float* means = ws;                       // 512
  float* stdev = ws + 512;                 // 512
  float* xr    = ws + 1024;                // 229376
  float* dec   = xr + 229376;              // 688128
  float* keyn  = dec + 688128;             // 768000
  double* kinv = (double*)(keyn + 768000); // 1000 doubles (pad to 2048 floats)
  float* xq    = keyn + 768000 + 2048;     // 344064
  float* of    = xq + 344064;              // 129024
  float* h     = of + 129024;              // 23396352  (30464 x 768)
  float* abuf  = h + 23396352;             // 23396352  (30464 x 768)
  float* scr   = abuf + 23396352;          // 11698176  (chunk scratch: qkv 8.77M / fc 11.7M)

  revin_kernel<<<448, 256, 0, stream>>>(x, xr, means, stdev);
  decompose_kernel<<<448, 256, 0, stream>>>(xr, dec);
  embed_kernel<<<NEMB, 256, 0, stream>>>(dec, in_w, in_b, h);
  keyn_kernel<<<1000, 256, 0, stream>>>(pkey, keyn, kinv);
  xq_kernel<<<448, 256, 0, stream>>>(h, xq);
  zero_kernel<<<1, 64, 0, stream>>>(out + 43008);
  simtopk_kernel<<<448, 256, 0, stream>>>(xq, pkey, kinv, keyn, wpe, h, out + 43008);
  addwpe_kernel<<<NEMB, 256, 0, stream>>>(wpe, h);

  for (int l = 0; l < 6; l++) {
    ln_kernel<<<NTOK, 256, 0, stream>>>(h, abuf, ln1_g + l * 768, ln1_b + l * 768);
    for (int c = 0; c < NCH; c++) {
      const float* Ain = abuf + (size_t)c * RCH * 768;
      sgemm_kernel<<<dim3(36, 30), 256, 0, stream>>>(
          Ain, qkv_w + (size_t)l * 768 * 2304, qkv_b + l * 2304, scr,
          RCH, 2304, 768, 0);
      attn_kernel<<<SCH * 12, 256, 0, stream>>>(scr, abuf + (size_t)c * RCH * 768);
    }
    sgemm_kernel<<<dim3(12, 238), 256, 0, stream>>>(
        abuf, aw + (size_t)l * 768 * 768, ab + l * 768, h,
        NTOK, 768, 768, FLAG_RESID);
    ln_kernel<<<NTOK, 256, 0, stream>>>(h, abuf, ln2_g + l * 768, ln2_b + l * 768);
    for (int c = 0; c < NCH; c++) {
      const float* Ain = abuf + (size_t)c * RCH * 768;
      sgemm_kernel<<<dim3(48, 30), 256, 0, stream>>>(
          Ain, fc_w + (size_t)l * 768 * 3072, fc_b + l * 3072, scr,
          RCH, 3072, 768, FLAG_GELU);
      sgemm_kernel<<<dim3(12, 30), 256, 0, stream>>>(
          scr, mp_w + (size_t)l * 3072 * 768, mp_b + l * 768, h + (size_t)c * RCH * 768,
          RCH, 768, 3072, FLAG_RESID);
    }
  }
  ln_kernel<<<NTOK, 256, 0, stream>>>(h, abuf, lnf_g, lnf_b);
  // ln(h) viewed as (1344, 17408) @ out_w(17408, 96)
  sgemm_kernel<<<dim3(2, 11), 256, 0, stream>>>(abuf, out_w, out_b, of,
                                                1344, 96, 17408, 0);
  combine_kernel<<<448, 96, 0, stream>>>(of, stdev, means, out);
}

// Round 3
// 12918.211 us; speedup vs baseline: 4.0740x; 4.0740x over previous
//
#include <hip/hip_runtime.h>
#include <math.h>

// ---------------- constants ----------------
#define NTOK 30464    // 448*68
#define NEMB 28672    // 448*64
#define NCH 7         // chunks
#define SCH 64        // series per chunk (448/7)
#define RCH 4352      // token rows per chunk (64*68) = 34*128
typedef unsigned short ushort;
typedef __attribute__((ext_vector_type(8))) __bf16 bf16x8_t;
typedef __attribute__((ext_vector_type(4))) float f32x4_t;

// ---------------- helpers ----------------
__device__ __forceinline__ ushort f2bf(float f) {
  unsigned int u = __float_as_uint(f);
  u += 0x7fffu + ((u >> 16) & 1u);   // RNE (finite inputs)
  return (ushort)(u >> 16);
}
__device__ __forceinline__ float bf2f(ushort u) {
  return __uint_as_float(((unsigned int)u) << 16);
}

__device__ __forceinline__ float block_reduce_sum(float v, float* scratch) {
  __syncthreads();
  #pragma unroll
  for (int o = 32; o; o >>= 1) v += __shfl_xor(v, o, 64);
  int wid = threadIdx.x >> 6, lane = threadIdx.x & 63;
  if (lane == 0) scratch[wid] = v;
  __syncthreads();
  if (threadIdx.x == 0) {
    float s = 0.f;
    int nw = (blockDim.x + 63) >> 6;
    for (int i = 0; i < nw; i++) s += scratch[i];
    scratch[0] = s;
  }
  __syncthreads();
  return scratch[0];
}

__device__ __forceinline__ float gelu_f(float x) {
  float x3 = x * x * x;
  return 0.5f * x * (1.0f + tanhf(0.7978845608028654f * (x + 0.044715f * x3)));
}

// ---------------- RevIN ----------------
__global__ __launch_bounds__(256) void revin_kernel(const float* __restrict__ x,
    float* __restrict__ xr, float* __restrict__ means, float* __restrict__ stdev) {
  int bm = blockIdx.x;
  int b = bm / 7, m = bm % 7;
  int tid = threadIdx.x;
  __shared__ float red[8];
  float v0 = x[(size_t)b * 3584 + (size_t)tid * 7 + m];
  float v1 = x[(size_t)b * 3584 + (size_t)(tid + 256) * 7 + m];
  float s  = block_reduce_sum(v0 + v1, red);
  float ss = block_reduce_sum(v0 * v0 + v1 * v1, red);
  float mean = s * (1.0f / 512.0f);
  float var  = ss * (1.0f / 512.0f) - mean * mean;
  float sd = sqrtf(var + 1e-5f);
  if (tid == 0) { means[bm] = mean; stdev[bm] = sd; }
  float inv = 1.0f / sd;
  xr[(size_t)bm * 512 + tid]       = (v0 - mean) * inv;
  xr[(size_t)bm * 512 + tid + 256] = (v1 - mean) * inv;
}

// ---------------- decompose ----------------
__global__ __launch_bounds__(256) void decompose_kernel(const float* __restrict__ xr,
    float* __restrict__ dec) {
  int n = blockIdx.x, tid = threadIdx.x;
  __shared__ float xv[512];
  __shared__ float tr[512];
  __shared__ float sumS[24];
  for (int l = tid; l < 512; l += 256) xv[l] = xr[(size_t)n * 512 + l];
  if (tid < 24) sumS[tid] = 0.f;
  __syncthreads();
  for (int l = tid; l < 512; l += 256) {
    int t0 = l - 12; t0 = t0 < 0 ? 0 : (t0 > 488 ? 488 : t0);
    float s = 0.f;
    #pragma unroll
    for (int j = 0; j < 24; j++) s += xv[t0 + j];
    float t = s * (1.0f / 24.0f);
    tr[l] = t;
    atomicAdd(&sumS[l % 24], xv[l] - t);
  }
  __syncthreads();
  if (tid < 24) sumS[tid] *= (tid < 8) ? (1.0f / 22.0f) : (1.0f / 21.0f);
  __syncthreads();
  float* dp = dec + (size_t)n * 1536;
  for (int l = tid; l < 512; l += 256) {
    float t = tr[l], se = sumS[l % 24];
    dp[l] = t;
    dp[512 + l] = se;
    dp[1024 + l] = xv[l] - t - se;
  }
}

// ---------------- patch + embed -> h rows 4..67 (NO wpe yet) ----------------
__global__ __launch_bounds__(256) void embed_kernel(const float* __restrict__ dec,
    const float* __restrict__ in_w, const float* __restrict__ in_b, float* __restrict__ h) {
  int np = blockIdx.x;
  int n = np >> 6, p = np & 63;
  int tid = threadIdx.x;
  __shared__ float tok[48];
  if (tid < 48) {
    int c = tid >> 4, j = tid & 15;
    int l = p * 8 + j; if (l > 511) l = 511;
    tok[tid] = dec[(size_t)n * 1536 + (size_t)c * 512 + l];
  }
  __syncthreads();
  float* outp = h + ((size_t)n * 68 + 4 + p) * 768;
  #pragma unroll
  for (int i = 0; i < 3; i++) {
    int d = tid + i * 256;
    float acc = in_b[d];
    #pragma unroll
    for (int k = 0; k < 48; k++) acc += tok[k] * in_w[(size_t)k * 768 + d];
    outp[d] = acc;
  }
}

// ---------------- key normalization ----------------
__global__ __launch_bounds__(256) void keyn_kernel(const float* __restrict__ pkey,
    float* __restrict__ keyn, double* __restrict__ kinv) {
  int k = blockIdx.x, tid = threadIdx.x;
  __shared__ double redd[4];
  float v[3];
  double ss = 0.0;
  #pragma unroll
  for (int i = 0; i < 3; i++) {
    v[i] = pkey[(size_t)k * 768 + tid + i * 256];
    ss += (double)v[i] * (double)v[i];
  }
  #pragma unroll
  for (int o = 32; o; o >>= 1) ss += __shfl_xor(ss, o, 64);
  int wid = tid >> 6, lane = tid & 63;
  if (lane == 0) redd[wid] = ss;
  __syncthreads();
  if (tid == 0) redd[0] = redd[0] + redd[1] + redd[2] + redd[3];
  __syncthreads();
  ss = redd[0];
  double inv = 1.0 / sqrt(ss > 1e-12 ? ss : 1e-12);
  #pragma unroll
  for (int i = 0; i < 3; i++)
    keyn[(size_t)k * 768 + tid + i * 256] = (float)((double)v[i] * inv);
  if (tid == 0) kinv[k] = inv;
}

// ---------------- xq ----------------
__global__ __launch_bounds__(256) void xq_kernel(const float* __restrict__ h,
    float* __restrict__ xq) {
  int n = blockIdx.x, tid = threadIdx.x;
  __shared__ float red[8];
  float vals[3];
  float ssl = 0.f;
  #pragma unroll
  for (int i = 0; i < 3; i++) {
    int d = tid + i * 256;
    const float* p = h + ((size_t)n * 68 + 4) * 768 + d;
    float s = 0.f;
    for (int pc = 0; pc < 64; pc++) s += p[(size_t)pc * 768];
    s *= (1.0f / 64.0f);
    vals[i] = s; ssl += s * s;
  }
  float ss = block_reduce_sum(ssl, red);
  float inv = rsqrtf(fmaxf(ss, 1e-12f));
  #pragma unroll
  for (int i = 0; i < 3; i++)
    xq[(size_t)n * 768 + tid + i * 256] = vals[i] * inv;
}

__global__ void zero_kernel(float* p) {
  if (threadIdx.x == 0 && blockIdx.x == 0) p[0] = 0.f;
}

// ---------------- sim (f64) + top-4 + prompt rows + reduce_sim ----------------
__global__ __launch_bounds__(256) void simtopk_kernel(
    const float* __restrict__ xq, const float* __restrict__ pkey,
    const double* __restrict__ kinv, const float* __restrict__ keyn,
    const float* __restrict__ wpe, float* __restrict__ h, float* __restrict__ rs_out) {
  int n = blockIdx.x, tid = threadIdx.x;
  __shared__ __align__(16) float xqv[768];
  __shared__ double simd_s[1000];
  __shared__ int idxs[4];
  __shared__ double redv[4];
  __shared__ int redi[4];
  __shared__ float red2[8];
  #pragma unroll
  for (int i = 0; i < 3; i++) xqv[tid + i * 256] = xq[(size_t)n * 768 + tid + i * 256];
  __syncthreads();
  for (int k = tid; k < 1000; k += 256) {
    const float* kp = pkey + (size_t)k * 768;
    double acc = 0.0;
    for (int d = 0; d < 768; d++) acc += (double)kp[d] * (double)xqv[d];
    simd_s[k] = acc * kinv[k];
  }
  __syncthreads();
  int lane = tid & 63, wid = tid >> 6;
  for (int r = 0; r < 4; r++) {
    double bv = -1e300; int bi = 0x7fffffff;
    for (int k = tid; k < 1000; k += 256) {
      double v = simd_s[k];
      if (v > bv || (v == bv && k < bi)) { bv = v; bi = k; }
    }
    #pragma unroll
    for (int off = 32; off; off >>= 1) {
      double ov = __shfl_xor(bv, off, 64);
      int oi = __shfl_xor(bi, off, 64);
      if (ov > bv || (ov == bv && oi < bi)) { bv = ov; bi = oi; }
    }
    if (lane == 0) { redv[wid] = bv; redi[wid] = bi; }
    __syncthreads();
    if (tid == 0) {
      double fv = redv[0]; int fi = redi[0];
      for (int w = 1; w < 4; w++)
        if (redv[w] > fv || (redv[w] == fv && redi[w] < fi)) { fv = redv[w]; fi = redi[w]; }
      idxs[r] = fi; simd_s[fi] = -1e300;
    }
    __syncthreads();
  }
  float part = 0.f;
  for (int r = 0; r < 4; r++) {
    int ki = idxs[r];
    const float* kp = keyn + (size_t)ki * 768;
    const float* wp = wpe + (size_t)r * 768;
    float* hp = h + ((size_t)n * 68 + r) * 768;
    #pragma unroll
    for (int i = 0; i < 3; i++) {
      int d = tid + i * 256;
      float kv = kp[d];
      hp[d] = kv + wp[d];
      part += kv * xqv[d];
    }
  }
  part = block_reduce_sum(part, red2);
  if (tid == 0) atomicAdd(rs_out, part * (1.0f / 448.0f));
}

// ---------------- h rows 4..67 += wpe ----------------
__global__ __launch_bounds__(256) void addwpe_kernel(const float* __restrict__ wpe,
    float* __restrict__ h) {
  int np = blockIdx.x;
  int n = np >> 6, p = np & 63;
  int tid = threadIdx.x;
  const float* wp = wpe + (size_t)(4 + p) * 768;
  float* hp = h + ((size_t)n * 68 + 4 + p) * 768;
  #pragma unroll
  for (int i = 0; i < 3; i++) { int d = tid + i * 256; hp[d] += wp[d]; }
}

// ---------------- LayerNorm -> bf16 ----------------
__global__ __launch_bounds__(256) void ln_kernel(const float* __restrict__ src,
    ushort* __restrict__ dst, const float* __restrict__ g, const float* __restrict__ b) {
  size_t row = blockIdx.x;
  const float* xp = src + row * 768;
  ushort* yp = dst + row * 768;
  int tid = threadIdx.x;
  float v0 = xp[tid], v1 = xp[tid + 256], v2 = xp[tid + 512];
  __shared__ float red[8];
  float s  = block_reduce_sum(v0 + v1 + v2, red);
  float ss = block_reduce_sum(v0 * v0 + v1 * v1 + v2 * v2, red);
  float mean = s * (1.0f / 768.0f);
  float var  = ss * (1.0f / 768.0f) - mean * mean;
  float rs = rsqrtf(var + 1e-5f);
  yp[tid]       = f2bf((v0 - mean) * rs * g[tid]       + b[tid]);
  yp[tid + 256] = f2bf((v1 - mean) * rs * g[tid + 256] + b[tid + 256]);
  yp[tid + 512] = f2bf((v2 - mean) * rs * g[tid + 512] + b[tid + 512]);
}

// ---------------- cast+transpose weights: W[K][N] f32 -> WT[N][K] bf16 ----------------
__global__ __launch_bounds__(256) void tcast_kernel(const float* __restrict__ W,
    ushort* __restrict__ WT, int K, int N) {
  __shared__ ushort t[32][33];
  int n0 = blockIdx.x * 32, k0 = blockIdx.y * 32;
  int tx = threadIdx.x & 31, ty = threadIdx.x >> 5;   // 32 x 8
  #pragma unroll
  for (int i = 0; i < 4; i++) {
    int kk = ty + i * 8;
    t[kk][tx] = f2bf(W[(size_t)(k0 + kk) * N + n0 + tx]);
  }
  __syncthreads();
  #pragma unroll
  for (int i = 0; i < 4; i++) {
    int nn = ty + i * 8;
    WT[(size_t)(n0 + nn) * K + k0 + tx] = t[tx][nn];
  }
}

// ---------------- bf16 MFMA GEMM: C = A(MxK) @ WT(NxK)^T + bias ----------------
// 128x128 tile, 256 threads (4 waves), 16x16x32 bf16 MFMA, 4x4 tiles/wave.
// mode 0: C bf16;  1: C bf16 w/ gelu;  2: C fp32 += (residual)
__global__ __launch_bounds__(256) void mfma_gemm(const ushort* __restrict__ A,
    const ushort* __restrict__ WT, const float* __restrict__ bias, void* __restrict__ Cp,
    int M, int N, int K, int mode) {
  __shared__ ushort As[128 * 40];   // [m][k], row stride 40 (80B, 16B-aligned, 2-way banks)
  __shared__ ushort Bs[128 * 40];   // [n][k]
  const int tid = threadIdx.x;
  const int row0 = blockIdx.y * 128, col0 = blockIdx.x * 128;
  const int w = tid >> 6, lane = tid & 63;
  const int wm = w >> 1, wn = w & 1;
  const int lm = lane & 15, quad = lane >> 4;
  const int sm = tid >> 2, sseg = (tid & 3) * 8;
  f32x4_t acc[4][4];
  #pragma unroll
  for (int mi = 0; mi < 4; mi++)
    #pragma unroll
    for (int ni = 0; ni < 4; ni++) acc[mi][ni] = (f32x4_t)(0.0f);

  for (int kb = 0; kb < K; kb += 32) {
    __syncthreads();
    uint4 va0 = *(const uint4*)(A  + (size_t)(row0 + sm)      * K + kb + sseg);
    uint4 va1 = *(const uint4*)(A  + (size_t)(row0 + sm + 64) * K + kb + sseg);
    uint4 vb0 = *(const uint4*)(WT + (size_t)(col0 + sm)      * K + kb + sseg);
    uint4 vb1 = *(const uint4*)(WT + (size_t)(col0 + sm + 64) * K + kb + sseg);
    *(uint4*)&As[sm * 40 + sseg]        = va0;
    *(uint4*)&As[(sm + 64) * 40 + sseg] = va1;
    *(uint4*)&Bs[sm * 40 + sseg]        = vb0;
    *(uint4*)&Bs[(sm + 64) * 40 + sseg] = vb1;
    __syncthreads();
    bf16x8_t af[4], bfr[4];
    #pragma unroll
    for (int mi = 0; mi < 4; mi++)
      af[mi] = *(const bf16x8_t*)&As[(wm * 64 + mi * 16 + lm) * 40 + quad * 8];
    #pragma unroll
    for (int ni = 0; ni < 4; ni++)
      bfr[ni] = *(const bf16x8_t*)&Bs[(wn * 64 + ni * 16 + lm) * 40 + quad * 8];
    #pragma unroll
    for (int mi = 0; mi < 4; mi++)
      #pragma unroll
      for (int ni = 0; ni < 4; ni++)
        acc[mi][ni] = __builtin_amdgcn_mfma_f32_16x16x32_bf16(af[mi], bfr[ni], acc[mi][ni], 0, 0, 0);
  }
  #pragma unroll
  for (int mi = 0; mi < 4; mi++) {
    #pragma unroll
    for (int ni = 0; ni < 4; ni++) {
      int gcol = col0 + wn * 64 + ni * 16 + lm;
      float bz = bias[gcol];
      #pragma unroll
      for (int r = 0; r < 4; r++) {
        int grow = row0 + wm * 64 + mi * 16 + quad * 4 + r;
        float v = acc[mi][ni][r] + bz;
        if (mode == 0)      ((ushort*)Cp)[(size_t)grow * N + gcol] = f2bf(v);
        else if (mode == 1) ((ushort*)Cp)[(size_t)grow * N + gcol] = f2bf(gelu_f(v));
        else { float* c = (float*)Cp + (size_t)grow * N + gcol; *c += v; }
      }
    }
  }
}

// ---------------- attention over one chunk (bf16 in/out) ----------------
__global__ __launch_bounds__(256) void attn_kernel(const ushort* __restrict__ qkvc,
    ushort* __restrict__ obase) {
  __shared__ float qs[68][65];
  __shared__ float ks[68][65];
  __shared__ float vs[68][65];
  int nh = blockIdx.x;
  int nl = nh / 12, hh = nh % 12;
  int tid = threadIdx.x;
  const ushort* base = qkvc + (size_t)nl * 68 * 2304 + hh * 64;
  for (int idx = tid; idx < 68 * 64; idx += 256) {
    int t = idx >> 6, d = idx & 63;
    const ushort* rp = base + (size_t)t * 2304 + d;
    qs[t][d] = bf2f(rp[0]);
    ks[t][d] = bf2f(rp[768]);
    vs[t][d] = bf2f(rp[1536]);
  }
  __syncthreads();
  int wid = tid >> 6, lane = tid & 63;
  for (int qt = wid; qt < 68; qt += 4) {
    float s1 = -1e30f, s2 = -1e30f;
    if (lane <= qt) {
      float acc = 0.f;
      #pragma unroll
      for (int d = 0; d < 64; d++) acc += qs[qt][d] * ks[lane][d];
      s1 = acc * 0.125f;
    }
    if (lane < 4 && 64 + lane <= qt) {
      float acc = 0.f;
      #pragma unroll
      for (int d = 0; d < 64; d++) acc += qs[qt][d] * ks[64 + lane][d];
      s2 = acc * 0.125f;
    }
    float mx = fmaxf(s1, s2);
    #pragma unroll
    for (int off = 32; off; off >>= 1) mx = fmaxf(mx, __shfl_xor(mx, off, 64));
    float e1 = (lane <= qt) ? __expf(s1 - mx) : 0.f;
    float e2 = (lane < 4 && 64 + lane <= qt) ? __expf(s2 - mx) : 0.f;
    float sum = e1 + e2;
    #pragma unroll
    for (int off = 32; off; off >>= 1) sum += __shfl_xor(sum, off, 64);
    float inv = 1.0f / sum;
    float a1 = e1 * inv, a2 = e2 * inv;
    float oacc = 0.f;
    int d = lane;
    int kmax1 = qt < 63 ? qt : 63;
    for (int kt = 0; kt <= kmax1; kt++) oacc += __shfl(a1, kt, 64) * vs[kt][d];
    for (int kt = 64; kt <= qt; kt++)   oacc += __shfl(a2, kt - 64, 64) * vs[kt][d];
    obase[((size_t)nl * 68 + qt) * 768 + hh * 64 + d] = f2bf(oacc);
  }
}

// ---------------- final head: of init w/ bias ----------------
__global__ __launch_bounds__(256) void initof_kernel(const float* __restrict__ ob,
    float* __restrict__ of) {
  int i = blockIdx.x * 256 + threadIdx.x;   // < 129024
  of[i] = ob[i % 96];
}

// ---------------- final head: split-K GEMM (1344 x 96, K=17408) ----------------
__global__ __launch_bounds__(256) void splitk_kernel(const ushort* __restrict__ A,
    const ushort* __restrict__ WT, float* __restrict__ of) {
  __shared__ ushort As[64][40];
  __shared__ ushort Ws[96][40];
  int row0 = blockIdx.x * 64;
  int k0 = blockIdx.y * 1024;
  int tid = threadIdx.x;
  int tx = tid & 15, ty = tid >> 4;
  float acc[4][6] = {};
  for (int kb = k0; kb < k0 + 1024; kb += 32) {
    __syncthreads();
    {
      int m = tid >> 2, seg = (tid & 3) * 8;
      uint4 v = *(const uint4*)(A + (size_t)(row0 + m) * 17408 + kb + seg);
      *(uint4*)&As[m][seg] = v;
    }
    for (int idx = tid; idx < 384; idx += 256) {
      int n = idx >> 2, seg = (idx & 3) * 8;
      uint4 v = *(const uint4*)(WT + (size_t)n * 17408 + kb + seg);
      *(uint4*)&Ws[n][seg] = v;
    }
    __syncthreads();
    for (int k = 0; k < 32; k++) {
      float av[4], wv[6];
      #pragma unroll
      for (int i = 0; i < 4; i++) av[i] = bf2f(As[ty * 4 + i][k]);
      #pragma unroll
      for (int j = 0; j < 6; j++) wv[j] = bf2f(Ws[tx * 6 + j][k]);
      #pragma unroll
      for (int i = 0; i < 4; i++)
        #pragma unroll
        for (int j = 0; j < 6; j++) acc[i][j] += av[i] * wv[j];
    }
  }
  #pragma unroll
  for (int i = 0; i < 4; i++)
    #pragma unroll
    for (int j = 0; j < 6; j++)
      atomicAdd(&of[(size_t)(row0 + ty * 4 + i) * 96 + tx * 6 + j], acc[i][j]);
}

// ---------------- final combine ----------------
__global__ void combine_kernel(const float* __restrict__ of, const float* __restrict__ stdev,
    const float* __restrict__ means, float* __restrict__ out) {
  int bm = blockIdx.x;
  int b = bm / 7, m = bm % 7;
  int j = threadIdx.x;
  if (j < 96) {
    float s = of[(size_t)(bm * 3 + 0) * 96 + j]
            + of[(size_t)(bm * 3 + 1) * 96 + j]
            + of[(size_t)(bm * 3 + 2) * 96 + j];
    out[(size_t)b * 672 + (size_t)j * 7 + m] = s * stdev[bm] + means[bm];
  }
}

// ---------------- launcher ----------------
extern "C" void kernel_launch(void* const* d_in, const int* in_sizes, int n_in,
                              void* d_out, int out_size, void* d_ws, size_t ws_size,
                              hipStream_t stream) {
  (void)in_sizes; (void)n_in; (void)out_size; (void)ws_size;
  const float* x     = (const float*)d_in[0];
  const float* in_w  = (const float*)d_in[2];
  const float* in_b  = (const float*)d_in[3];
  const float* pkey  = (const float*)d_in[4];
  const float* wpe   = (const float*)d_in[5];
  const float* ln1_g = (const float*)d_in[6];
  const float* ln1_b = (const float*)d_in[7];
  const float* qkv_w = (const float*)d_in[8];
  const float* qkv_b = (const float*)d_in[9];
  const float* aw    = (const float*)d_in[10];
  const float* ab    = (const float*)d_in[11];
  const float* ln2_g = (const float*)d_in[12];
  const float* ln2_b = (const float*)d_in[13];
  const float* fc_w  = (const float*)d_in[14];
  const float* fc_b  = (const float*)d_in[15];
  const float* mp_w  = (const float*)d_in[16];
  const float* mp_b  = (const float*)d_in[17];
  const float* lnf_g = (const float*)d_in[18];
  const float* lnf_b = (const float*)d_in[19];
  const float* out_w = (const float*)d_in[20];
  const float* out_b = (const float*)d_in[21];
  float* out = (float*)d_out;
  float* ws  = (float*)d_ws;

  // workspace layout — ~193 MB total
  float* means = ws;                        // 512
  float* stdev = ws + 512;                  // 512
  float* xr    = ws + 1024;                 // 229376
  float* dec   = xr + 229376;               // 688128
  float* keyn  = dec + 688128;              // 768000
  double* kinv = (double*)(keyn + 768000);  // 1000 doubles (2048 floats)
  float* xq    = keyn + 768000 + 2048;      // 344064
  float* of    = xq + 344064;               // 129024
  float* h     = of + 129024;               // 23396352 f (30464 x 768)
  ushort* abuf16 = (ushort*)(h + 23396352); // 23396352 us (30464 x 768)
  ushort* scr16  = abuf16 + 23396352;       // 13369344 us (4352 x 3072 max)
  ushort* w16    = scr16 + 13369344;        // 7077888 us (per-layer weights)
  ushort* owT16  = w16 + 7077888;           // 1671168 us (96 x 17408)

  ushort* wqT  = w16;                          // 2304 x 768
  ushort* waT  = wqT + 2304 * 768;             // 768 x 768
  ushort* wfcT = waT + 768 * 768;              // 3072 x 768
  ushort* wmpT = wfcT + 3072 * 768;            // 768 x 3072

  revin_kernel<<<448, 256, 0, stream>>>(x, xr, means, stdev);
  decompose_kernel<<<448, 256, 0, stream>>>(xr, dec);
  embed_kernel<<<NEMB, 256, 0, stream>>>(dec, in_w, in_b, h);
  keyn_kernel<<<1000, 256, 0, stream>>>(pkey, keyn, kinv);
  xq_kernel<<<448, 256, 0, stream>>>(h, xq);
  zero_kernel<<<1, 64, 0, stream>>>(out + 43008);
  simtopk_kernel<<<448, 256, 0, stream>>>(xq, pkey, kinv, keyn, wpe, h, out + 43008);
  addwpe_kernel<<<NEMB, 256, 0, stream>>>(wpe, h);

  for (int l = 0; l < 6; l++) {
    tcast_kernel<<<dim3(72, 24), 256, 0, stream>>>(qkv_w + (size_t)l * 768 * 2304, wqT, 768, 2304);
    tcast_kernel<<<dim3(24, 24), 256, 0, stream>>>(aw    + (size_t)l * 768 * 768,  waT, 768, 768);
    tcast_kernel<<<dim3(96, 24), 256, 0, stream>>>(fc_w  + (size_t)l * 768 * 3072, wfcT, 768, 3072);
    tcast_kernel<<<dim3(24, 96), 256, 0, stream>>>(mp_w  + (size_t)l * 3072 * 768, wmpT, 3072, 768);

    ln_kernel<<<NTOK, 256, 0, stream>>>(h, abuf16, ln1_g + l * 768, ln1_b + l * 768);
    for (int c = 0; c < NCH; c++) {
      mfma_gemm<<<dim3(18, 34), 256, 0, stream>>>(
          abuf16 + (size_t)c * RCH * 768, wqT, qkv_b + l * 2304, scr16,
          RCH, 2304, 768, 0);
      attn_kernel<<<SCH * 12, 256, 0, stream>>>(scr16, abuf16 + (size_t)c * RCH * 768);
    }
    mfma_gemm<<<dim3(6, 238), 256, 0, stream>>>(
        abuf16, waT, ab + l * 768, h, NTOK, 768, 768, 2);
    ln_kernel<<<NTOK, 256, 0, stream>>>(h, abuf16, ln2_g + l * 768, ln2_b + l * 768);
    for (int c = 0; c < NCH; c++) {
      mfma_gemm<<<dim3(24, 34), 256, 0, stream>>>(
          abuf16 + (size_t)c * RCH * 768, wfcT, fc_b + l * 3072, scr16,
          RCH, 3072, 768, 1);
      mfma_gemm<<<dim3(6, 34), 256, 0, stream>>>(
          scr16, wmpT, mp_b + l * 768, h + (size_t)c * RCH * 768,
          RCH, 768, 3072, 2);
    }
  }
  ln_kernel<<<NTOK, 256, 0, stream>>>(h, abuf16, lnf_g, lnf_b);
  tcast_kernel<<<dim3(3, 544), 256, 0, stream>>>(out_w, owT16, 17408, 96);
  initof_kernel<<<504, 256, 0, stream>>>(out_b, of);
  splitk_kernel<<<dim3(21, 17), 256, 0, stream>>>(abuf16, owT16, of);
  combine_kernel<<<448, 96, 0, stream>>>(of, stdev, means, out);
}

// Round 4
// 10838.773 us; speedup vs baseline: 4.8556x; 1.1919x over previous
//
#include <hip/hip_runtime.h>
#include <math.h>

// ---------------- constants ----------------
#define NTOK 30464    // 448*68
#define NEMB 28672    // 448*64
#define NCH 7         // chunks
#define SCH 64        // series per chunk (448/7)
#define RCH 4352      // token rows per chunk (64*68) = 34*128
typedef unsigned short ushort;
typedef __attribute__((ext_vector_type(8))) __bf16 bf16x8_t;
typedef __attribute__((ext_vector_type(4))) float f32x4_t;

#if defined(__has_builtin)
#if __has_builtin(__builtin_amdgcn_global_load_lds)
#define HAS_GLL 1
#endif
#endif

// ---------------- helpers ----------------
__device__ __forceinline__ ushort f2bf(float f) {
  unsigned int u = __float_as_uint(f);
  u += 0x7fffu + ((u >> 16) & 1u);   // RNE (finite inputs)
  return (ushort)(u >> 16);
}
__device__ __forceinline__ float bf2f(ushort u) {
  return __uint_as_float(((unsigned int)u) << 16);
}

#ifdef HAS_GLL
__device__ __forceinline__ void gll16(const ushort* g, ushort* l) {
  __builtin_amdgcn_global_load_lds(
      (const __attribute__((address_space(1))) unsigned int*)g,
      (__attribute__((address_space(3))) unsigned int*)l, 16, 0, 0);
}
#endif

__device__ __forceinline__ float block_reduce_sum(float v, float* scratch) {
  __syncthreads();
  #pragma unroll
  for (int o = 32; o; o >>= 1) v += __shfl_xor(v, o, 64);
  int wid = threadIdx.x >> 6, lane = threadIdx.x & 63;
  if (lane == 0) scratch[wid] = v;
  __syncthreads();
  if (threadIdx.x == 0) {
    float s = 0.f;
    int nw = (blockDim.x + 63) >> 6;
    for (int i = 0; i < nw; i++) s += scratch[i];
    scratch[0] = s;
  }
  __syncthreads();
  return scratch[0];
}

__device__ __forceinline__ float gelu_f(float x) {
  float x3 = x * x * x;
  return 0.5f * x * (1.0f + tanhf(0.7978845608028654f * (x + 0.044715f * x3)));
}

// ---------------- RevIN ----------------
__global__ __launch_bounds__(256) void revin_kernel(const float* __restrict__ x,
    float* __restrict__ xr, float* __restrict__ means, float* __restrict__ stdev) {
  int bm = blockIdx.x;
  int b = bm / 7, m = bm % 7;
  int tid = threadIdx.x;
  __shared__ float red[8];
  float v0 = x[(size_t)b * 3584 + (size_t)tid * 7 + m];
  float v1 = x[(size_t)b * 3584 + (size_t)(tid + 256) * 7 + m];
  float s  = block_reduce_sum(v0 + v1, red);
  float ss = block_reduce_sum(v0 * v0 + v1 * v1, red);
  float mean = s * (1.0f / 512.0f);
  float var  = ss * (1.0f / 512.0f) - mean * mean;
  float sd = sqrtf(var + 1e-5f);
  if (tid == 0) { means[bm] = mean; stdev[bm] = sd; }
  float inv = 1.0f / sd;
  xr[(size_t)bm * 512 + tid]       = (v0 - mean) * inv;
  xr[(size_t)bm * 512 + tid + 256] = (v1 - mean) * inv;
}

// ---------------- decompose ----------------
__global__ __launch_bounds__(256) void decompose_kernel(const float* __restrict__ xr,
    float* __restrict__ dec) {
  int n = blockIdx.x, tid = threadIdx.x;
  __shared__ float xv[512];
  __shared__ float tr[512];
  __shared__ float sumS[24];
  for (int l = tid; l < 512; l += 256) xv[l] = xr[(size_t)n * 512 + l];
  if (tid < 24) sumS[tid] = 0.f;
  __syncthreads();
  for (int l = tid; l < 512; l += 256) {
    int t0 = l - 12; t0 = t0 < 0 ? 0 : (t0 > 488 ? 488 : t0);
    float s = 0.f;
    #pragma unroll
    for (int j = 0; j < 24; j++) s += xv[t0 + j];
    float t = s * (1.0f / 24.0f);
    tr[l] = t;
    atomicAdd(&sumS[l % 24], xv[l] - t);
  }
  __syncthreads();
  if (tid < 24) sumS[tid] *= (tid < 8) ? (1.0f / 22.0f) : (1.0f / 21.0f);
  __syncthreads();
  float* dp = dec + (size_t)n * 1536;
  for (int l = tid; l < 512; l += 256) {
    float t = tr[l], se = sumS[l % 24];
    dp[l] = t;
    dp[512 + l] = se;
    dp[1024 + l] = xv[l] - t - se;
  }
}

// ---------------- patch + embed -> h rows 4..67 (NO wpe yet) ----------------
__global__ __launch_bounds__(256) void embed_kernel(const float* __restrict__ dec,
    const float* __restrict__ in_w, const float* __restrict__ in_b, float* __restrict__ h) {
  int np = blockIdx.x;
  int n = np >> 6, p = np & 63;
  int tid = threadIdx.x;
  __shared__ float tok[48];
  if (tid < 48) {
    int c = tid >> 4, j = tid & 15;
    int l = p * 8 + j; if (l > 511) l = 511;
    tok[tid] = dec[(size_t)n * 1536 + (size_t)c * 512 + l];
  }
  __syncthreads();
  float* outp = h + ((size_t)n * 68 + 4 + p) * 768;
  #pragma unroll
  for (int i = 0; i < 3; i++) {
    int d = tid + i * 256;
    float acc = in_b[d];
    #pragma unroll
    for (int k = 0; k < 48; k++) acc += tok[k] * in_w[(size_t)k * 768 + d];
    outp[d] = acc;
  }
}

// ---------------- key normalization ----------------
__global__ __launch_bounds__(256) void keyn_kernel(const float* __restrict__ pkey,
    float* __restrict__ keyn, double* __restrict__ kinv) {
  int k = blockIdx.x, tid = threadIdx.x;
  __shared__ double redd[4];
  float v[3];
  double ss = 0.0;
  #pragma unroll
  for (int i = 0; i < 3; i++) {
    v[i] = pkey[(size_t)k * 768 + tid + i * 256];
    ss += (double)v[i] * (double)v[i];
  }
  #pragma unroll
  for (int o = 32; o; o >>= 1) ss += __shfl_xor(ss, o, 64);
  int wid = tid >> 6, lane = tid & 63;
  if (lane == 0) redd[wid] = ss;
  __syncthreads();
  if (tid == 0) redd[0] = redd[0] + redd[1] + redd[2] + redd[3];
  __syncthreads();
  ss = redd[0];
  double inv = 1.0 / sqrt(ss > 1e-12 ? ss : 1e-12);
  #pragma unroll
  for (int i = 0; i < 3; i++)
    keyn[(size_t)k * 768 + tid + i * 256] = (float)((double)v[i] * inv);
  if (tid == 0) kinv[k] = inv;
}

// ---------------- xq ----------------
__global__ __launch_bounds__(256) void xq_kernel(const float* __restrict__ h,
    float* __restrict__ xq) {
  int n = blockIdx.x, tid = threadIdx.x;
  __shared__ float red[8];
  float vals[3];
  float ssl = 0.f;
  #pragma unroll
  for (int i = 0; i < 3; i++) {
    int d = tid + i * 256;
    const float* p = h + ((size_t)n * 68 + 4) * 768 + d;
    float s = 0.f;
    for (int pc = 0; pc < 64; pc++) s += p[(size_t)pc * 768];
    s *= (1.0f / 64.0f);
    vals[i] = s; ssl += s * s;
  }
  float ss = block_reduce_sum(ssl, red);
  float inv = rsqrtf(fmaxf(ss, 1e-12f));
  #pragma unroll
  for (int i = 0; i < 3; i++)
    xq[(size_t)n * 768 + tid + i * 256] = vals[i] * inv;
}

__global__ void zero_kernel(float* p) {
  if (threadIdx.x == 0 && blockIdx.x == 0) p[0] = 0.f;
}

// ---------------- sim (f64, wave-per-key) + top-4 + prompt rows + reduce_sim ----------------
__global__ __launch_bounds__(256) void simtopk_kernel(
    const float* __restrict__ xq, const float* __restrict__ pkey,
    const double* __restrict__ kinv, const float* __restrict__ keyn,
    const float* __restrict__ wpe, float* __restrict__ h, float* __restrict__ rs_out) {
  int n = blockIdx.x, tid = threadIdx.x;
  __shared__ __align__(16) float xqv[768];
  __shared__ double simd_s[1000];
  __shared__ int idxs[4];
  __shared__ double redv[4];
  __shared__ int redi[4];
  __shared__ float red2[8];
  #pragma unroll
  for (int i = 0; i < 3; i++) xqv[tid + i * 256] = xq[(size_t)n * 768 + tid + i * 256];
  __syncthreads();
  int lane = tid & 63, wid = tid >> 6;
  for (int k = wid; k < 1000; k += 4) {
    const float* kp = pkey + (size_t)k * 768;
    double acc = 0.0;
    #pragma unroll
    for (int i = 0; i < 12; i++) {
      int d = lane + 64 * i;
      acc += (double)kp[d] * (double)xqv[d];
    }
    #pragma unroll
    for (int o = 32; o; o >>= 1) acc += __shfl_xor(acc, o, 64);
    if (lane == 0) simd_s[k] = acc * kinv[k];
  }
  __syncthreads();
  for (int r = 0; r < 4; r++) {
    double bv = -1e300; int bi = 0x7fffffff;
    for (int k = tid; k < 1000; k += 256) {
      double v = simd_s[k];
      if (v > bv || (v == bv && k < bi)) { bv = v; bi = k; }
    }
    #pragma unroll
    for (int off = 32; off; off >>= 1) {
      double ov = __shfl_xor(bv, off, 64);
      int oi = __shfl_xor(bi, off, 64);
      if (ov > bv || (ov == bv && oi < bi)) { bv = ov; bi = oi; }
    }
    if (lane == 0) { redv[wid] = bv; redi[wid] = bi; }
    __syncthreads();
    if (tid == 0) {
      double fv = redv[0]; int fi = redi[0];
      for (int w = 1; w < 4; w++)
        if (redv[w] > fv || (redv[w] == fv && redi[w] < fi)) { fv = redv[w]; fi = redi[w]; }
      idxs[r] = fi; simd_s[fi] = -1e300;
    }
    __syncthreads();
  }
  float part = 0.f;
  for (int r = 0; r < 4; r++) {
    int ki = idxs[r];
    const float* kp = keyn + (size_t)ki * 768;
    const float* wp = wpe + (size_t)r * 768;
    float* hp = h + ((size_t)n * 68 + r) * 768;
    #pragma unroll
    for (int i = 0; i < 3; i++) {
      int d = tid + i * 256;
      float kv = kp[d];
      hp[d] = kv + wp[d];
      part += kv * xqv[d];
    }
  }
  part = block_reduce_sum(part, red2);
  if (tid == 0) atomicAdd(rs_out, part * (1.0f / 448.0f));
}

// ---------------- h rows 4..67 += wpe ----------------
__global__ __launch_bounds__(256) void addwpe_kernel(const float* __restrict__ wpe,
    float* __restrict__ h) {
  int np = blockIdx.x;
  int n = np >> 6, p = np & 63;
  int tid = threadIdx.x;
  const float* wp = wpe + (size_t)(4 + p) * 768;
  float* hp = h + ((size_t)n * 68 + 4 + p) * 768;
  #pragma unroll
  for (int i = 0; i < 3; i++) { int d = tid + i * 256; hp[d] += wp[d]; }
}

// ---------------- LayerNorm -> bf16 ----------------
__global__ __launch_bounds__(256) void ln_kernel(const float* __restrict__ src,
    ushort* __restrict__ dst, const float* __restrict__ g, const float* __restrict__ b) {
  size_t row = blockIdx.x;
  const float* xp = src + row * 768;
  ushort* yp = dst + row * 768;
  int tid = threadIdx.x;
  float v0 = xp[tid], v1 = xp[tid + 256], v2 = xp[tid + 512];
  __shared__ float red[8];
  float s  = block_reduce_sum(v0 + v1 + v2, red);
  float ss = block_reduce_sum(v0 * v0 + v1 * v1 + v2 * v2, red);
  float mean = s * (1.0f / 768.0f);
  float var  = ss * (1.0f / 768.0f) - mean * mean;
  float rs = rsqrtf(var + 1e-5f);
  yp[tid]       = f2bf((v0 - mean) * rs * g[tid]       + b[tid]);
  yp[tid + 256] = f2bf((v1 - mean) * rs * g[tid + 256] + b[tid + 256]);
  yp[tid + 512] = f2bf((v2 - mean) * rs * g[tid + 512] + b[tid + 512]);
}

// ---------------- cast+transpose weights: W[K][N] f32 -> WT[N][K] bf16 ----------------
__global__ __launch_bounds__(256) void tcast_kernel(const float* __restrict__ W,
    ushort* __restrict__ WT, int K, int N) {
  __shared__ ushort t[32][33];
  int n0 = blockIdx.x * 32, k0 = blockIdx.y * 32;
  int tx = threadIdx.x & 31, ty = threadIdx.x >> 5;   // 32 x 8
  #pragma unroll
  for (int i = 0; i < 4; i++) {
    int kk = ty + i * 8;
    t[kk][tx] = f2bf(W[(size_t)(k0 + kk) * N + n0 + tx]);
  }
  __syncthreads();
  #pragma unroll
  for (int i = 0; i < 4; i++) {
    int nn = ty + i * 8;
    WT[(size_t)(n0 + nn) * K + k0 + tx] = t[tx][nn];
  }
}

// ---------------- bf16 MFMA GEMM (m97-style global_load_lds staging) ----------------
// C = A(MxK) @ WT(NxK)^T + bias. 128x128 tile, 4 waves, 16x16x32 bf16.
// LDS [row][32] unpadded (64B rows) so wave-uniform-base + lane*16B staging lands right.
// mode 0: C bf16;  1: C bf16 w/ gelu;  2: C fp32 += (residual)
__global__ __launch_bounds__(256) void mfma_gemm(const ushort* __restrict__ A,
    const ushort* __restrict__ WT, const float* __restrict__ bias, void* __restrict__ Cp,
    int M, int N, int K, int mode) {
  __shared__ ushort As[128 * 32];
  __shared__ ushort Bs[128 * 32];
  const int tid = threadIdx.x;
  const int row0 = blockIdx.y * 128, col0 = blockIdx.x * 128;
  const int w = tid >> 6, lane = tid & 63;
  const int wm = w >> 1, wn = w & 1;
  const int lm = lane & 15, quad = lane >> 4;
  // staging: wave w covers tile-rows [w*16, w*16+16) and [64+w*16, ...)
  const int srow = w * 16 + (lane >> 2);
  const int scol = (lane & 3) * 8;
  const ushort* agp0 = A  + (size_t)(row0 + srow)      * K + scol;
  const ushort* agp1 = A  + (size_t)(row0 + 64 + srow) * K + scol;
  const ushort* bgp0 = WT + (size_t)(col0 + srow)      * K + scol;
  const ushort* bgp1 = WT + (size_t)(col0 + 64 + srow) * K + scol;
  ushort* al0 = &As[w * 512];
  ushort* al1 = &As[2048 + w * 512];
  ushort* bl0 = &Bs[w * 512];
  ushort* bl1 = &Bs[2048 + w * 512];
  f32x4_t acc[4][4];
  #pragma unroll
  for (int mi = 0; mi < 4; mi++)
    #pragma unroll
    for (int ni = 0; ni < 4; ni++) acc[mi][ni] = (f32x4_t)(0.0f);

  for (int kb = 0; kb < K; kb += 32) {
    __syncthreads();
#ifdef HAS_GLL
    gll16(agp0 + kb, al0);
    gll16(agp1 + kb, al1);
    gll16(bgp0 + kb, bl0);
    gll16(bgp1 + kb, bl1);
#else
    {
      uint4 va0 = *(const uint4*)(agp0 + kb);
      uint4 va1 = *(const uint4*)(agp1 + kb);
      uint4 vb0 = *(const uint4*)(bgp0 + kb);
      uint4 vb1 = *(const uint4*)(bgp1 + kb);
      *(uint4*)&al0[lane * 8] = va0;
      *(uint4*)&al1[lane * 8] = va1;
      *(uint4*)&bl0[lane * 8] = vb0;
      *(uint4*)&bl1[lane * 8] = vb1;
    }
#endif
    __syncthreads();
    bf16x8_t af[4], bfr[4];
    #pragma unroll
    for (int mi = 0; mi < 4; mi++)
      af[mi] = *(const bf16x8_t*)&As[(wm * 64 + mi * 16 + lm) * 32 + quad * 8];
    #pragma unroll
    for (int ni = 0; ni < 4; ni++)
      bfr[ni] = *(const bf16x8_t*)&Bs[(wn * 64 + ni * 16 + lm) * 32 + quad * 8];
    #pragma unroll
    for (int mi = 0; mi < 4; mi++)
      #pragma unroll
      for (int ni = 0; ni < 4; ni++)
        acc[mi][ni] = __builtin_amdgcn_mfma_f32_16x16x32_bf16(af[mi], bfr[ni], acc[mi][ni], 0, 0, 0);
  }
  #pragma unroll
  for (int mi = 0; mi < 4; mi++) {
    #pragma unroll
    for (int ni = 0; ni < 4; ni++) {
      int gcol = col0 + wn * 64 + ni * 16 + lm;
      float bz = bias[gcol];
      #pragma unroll
      for (int r = 0; r < 4; r++) {
        int grow = row0 + wm * 64 + mi * 16 + quad * 4 + r;
        float v = acc[mi][ni][r] + bz;
        if (mode == 0)      ((ushort*)Cp)[(size_t)grow * N + gcol] = f2bf(v);
        else if (mode == 1) ((ushort*)Cp)[(size_t)grow * N + gcol] = f2bf(gelu_f(v));
        else { float* c = (float*)Cp + (size_t)grow * N + gcol; *c += v; }
      }
    }
  }
}

// ---------------- MFMA attention: block = (series-in-chunk, head) ----------------
// S = QK^T (5x5 tiles of 16x16, K=64), mask+scale -> LDS f32, softmax,
// P(bf16, overlays Q/K LDS) @ V^T (5x4 tiles, K=96 padded w/ zeros).
__global__ __launch_bounds__(256) void attn_kernel(const ushort* __restrict__ qkvc,
    ushort* __restrict__ obase) {
  __shared__ __align__(16) ushort qk[2 * 80 * 64];   // qs rows 0..79, ks rows 0..79 (64B rows)
  __shared__ __align__(16) ushort vt[64][96];        // V^T, k-pad 68..95 zeroed (192B rows)
  __shared__ __align__(16) float  sS[68][80];        // masked scaled scores
  ushort* qs = qk;                  // [80][64]
  ushort* ks = qk + 80 * 64;        // [80][64]
  ushort (*P)[96] = (ushort(*)[96])qk;   // [80][96] bf16, valid after S phase

  int nh = blockIdx.x;
  int nl = nh / 12, hh = nh % 12;
  int tid = threadIdx.x;
  const int w = tid >> 6, lane = tid & 63;
  const int lm = lane & 15, quad = lane >> 4;
  const ushort* base = qkvc + (size_t)nl * 68 * 2304 + hh * 64;

  // stage Q, K (natural [t][d]) and V transposed [d][t]; zero vt k-pad
  for (int idx = tid; idx < 68 * 64; idx += 256) {
    int t = idx >> 6, d = idx & 63;
    const ushort* rp = base + (size_t)t * 2304 + d;
    qs[t * 64 + d] = rp[0];
    ks[t * 64 + d] = rp[768];
    vt[d][t] = rp[1536];
  }
  for (int idx = tid; idx < 64 * 28; idx += 256) {
    int d = idx / 28, t = 68 + idx % 28;
    vt[d][t] = 0;
  }
  __syncthreads();

  // S = Q @ K^T : 25 tiles round-robin over 4 waves
  for (int t5 = w; t5 < 25; t5 += 4) {
    int mi = t5 / 5, ni = t5 % 5;
    bf16x8_t a0 = *(const bf16x8_t*)&qs[(mi * 16 + lm) * 64 + quad * 8];
    bf16x8_t a1 = *(const bf16x8_t*)&qs[(mi * 16 + lm) * 64 + 32 + quad * 8];
    bf16x8_t b0 = *(const bf16x8_t*)&ks[(ni * 16 + lm) * 64 + quad * 8];
    bf16x8_t b1 = *(const bf16x8_t*)&ks[(ni * 16 + lm) * 64 + 32 + quad * 8];
    f32x4_t acc = (f32x4_t)(0.0f);
    acc = __builtin_amdgcn_mfma_f32_16x16x32_bf16(a0, b0, acc, 0, 0, 0);
    acc = __builtin_amdgcn_mfma_f32_16x16x32_bf16(a1, b1, acc, 0, 0, 0);
    int col = ni * 16 + lm;
    #pragma unroll
    for (int r = 0; r < 4; r++) {
      int row = mi * 16 + quad * 4 + r;
      if (row < 68) {
        float sv = (col > row || col >= 68) ? -1e9f : acc[r] * 0.125f;
        sS[row][col] = sv;
      }
    }
  }
  __syncthreads();   // S done; qk (qs/ks) now dead -> reusable as P

  // softmax rows; write P bf16 (incl. zero pads)
  if (tid < 68) {
    int r = tid;
    float mx = -1e30f;
    for (int c = 0; c < 80; c++) mx = fmaxf(mx, sS[r][c]);
    float sum = 0.f;
    for (int c = 0; c < 80; c++) { float e = __expf(sS[r][c] - mx); sS[r][c] = e; sum += e; }
    float inv = 1.0f / sum;
    for (int c = 0; c < 80; c++) P[r][c] = f2bf(sS[r][c] * inv);
    #pragma unroll
    for (int c = 80; c < 96; c++) P[r][c] = 0;
  } else if (tid < 80) {
    for (int c = 0; c < 96; c++) P[tid][c] = 0;
  }
  __syncthreads();

  // O = P @ V : 20 tiles (mi 0..4, ni 0..3), K=96
  for (int t5 = w; t5 < 20; t5 += 4) {
    int mi = t5 % 5, ni = t5 / 5;
    f32x4_t acc = (f32x4_t)(0.0f);
    #pragma unroll
    for (int kk = 0; kk < 3; kk++) {
      bf16x8_t a = *(const bf16x8_t*)&P[mi * 16 + lm][kk * 32 + quad * 8];
      bf16x8_t b = *(const bf16x8_t*)&vt[ni * 16 + lm][kk * 32 + quad * 8];
      acc = __builtin_amdgcn_mfma_f32_16x16x32_bf16(a, b, acc, 0, 0, 0);
    }
    int col = ni * 16 + lm;
    #pragma unroll
    for (int r = 0; r < 4; r++) {
      int row = mi * 16 + quad * 4 + r;
      if (row < 68)
        obase[((size_t)nl * 68 + row) * 768 + hh * 64 + col] = f2bf(acc[r]);
    }
  }
}

// ---------------- final head: of init w/ bias ----------------
__global__ __launch_bounds__(256) void initof_kernel(const float* __restrict__ ob,
    float* __restrict__ of) {
  int i = blockIdx.x * 256 + threadIdx.x;   // < 129024
  of[i] = ob[i % 96];
}

// ---------------- final head: split-K GEMM (1344 x 96, K=17408) ----------------
__global__ __launch_bounds__(256) void splitk_kernel(const ushort* __restrict__ A,
    const ushort* __restrict__ WT, float* __restrict__ of) {
  __shared__ ushort As[64][40];
  __shared__ ushort Ws[96][40];
  int row0 = blockIdx.x * 64;
  int k0 = blockIdx.y * 1024;
  int tid = threadIdx.x;
  int tx = tid & 15, ty = tid >> 4;
  float acc[4][6] = {};
  for (int kb = k0; kb < k0 + 1024; kb += 32) {
    __syncthreads();
    {
      int m = tid >> 2, seg = (tid & 3) * 8;
      uint4 v = *(const uint4*)(A + (size_t)(row0 + m) * 17408 + kb + seg);
      *(uint4*)&As[m][seg] = v;
    }
    for (int idx = tid; idx < 384; idx += 256) {
      int n = idx >> 2, seg = (idx & 3) * 8;
      uint4 v = *(const uint4*)(WT + (size_t)n * 17408 + kb + seg);
      *(uint4*)&Ws[n][seg] = v;
    }
    __syncthreads();
    for (int k = 0; k < 32; k++) {
      float av[4], wv[6];
      #pragma unroll
      for (int i = 0; i < 4; i++) av[i] = bf2f(As[ty * 4 + i][k]);
      #pragma unroll
      for (int j = 0; j < 6; j++) wv[j] = bf2f(Ws[tx * 6 + j][k]);
      #pragma unroll
      for (int i = 0; i < 4; i++)
        #pragma unroll
        for (int j = 0; j < 6; j++) acc[i][j] += av[i] * wv[j];
    }
  }
  #pragma unroll
  for (int i = 0; i < 4; i++)
    #pragma unroll
    for (int j = 0; j < 6; j++)
      atomicAdd(&of[(size_t)(row0 + ty * 4 + i) * 96 + tx * 6 + j], acc[i][j]);
}

// ---------------- final combine ----------------
__global__ void combine_kernel(const float* __restrict__ of, const float* __restrict__ stdev,
    const float* __restrict__ means, float* __restrict__ out) {
  int bm = blockIdx.x;
  int b = bm / 7, m = bm % 7;
  int j = threadIdx.x;
  if (j < 96) {
    float s = of[(size_t)(bm * 3 + 0) * 96 + j]
            + of[(size_t)(bm * 3 + 1) * 96 + j]
            + of[(size_t)(bm * 3 + 2) * 96 + j];
    out[(size_t)b * 672 + (size_t)j * 7 + m] = s * stdev[bm] + means[bm];
  }
}

// ---------------- launcher ----------------
extern "C" void kernel_launch(void* const* d_in, const int* in_sizes, int n_in,
                              void* d_out, int out_size, void* d_ws, size_t ws_size,
                              hipStream_t stream) {
  (void)in_sizes; (void)n_in; (void)out_size; (void)ws_size;
  const float* x     = (const float*)d_in[0];
  const float* in_w  = (const float*)d_in[2];
  const float* in_b  = (const float*)d_in[3];
  const float* pkey  = (const float*)d_in[4];
  const float* wpe   = (const float*)d_in[5];
  const float* ln1_g = (const float*)d_in[6];
  const float* ln1_b = (const float*)d_in[7];
  const float* qkv_w = (const float*)d_in[8];
  const float* qkv_b = (const float*)d_in[9];
  const float* aw    = (const float*)d_in[10];
  const float* ab    = (const float*)d_in[11];
  const float* ln2_g = (const float*)d_in[12];
  const float* ln2_b = (const float*)d_in[13];
  const float* fc_w  = (const float*)d_in[14];
  const float* fc_b  = (const float*)d_in[15];
  const float* mp_w  = (const float*)d_in[16];
  const float* mp_b  = (const float*)d_in[17];
  const float* lnf_g = (const float*)d_in[18];
  const float* lnf_b = (const float*)d_in[19];
  const float* out_w = (const float*)d_in[20];
  const float* out_b = (const float*)d_in[21];
  float* out = (float*)d_out;
  float* ws  = (float*)d_ws;

  // workspace layout — ~193 MB total
  float* means = ws;                        // 512
  float* stdev = ws + 512;                  // 512
  float* xr    = ws + 1024;                 // 229376
  float* dec   = xr + 229376;               // 688128
  float* keyn  = dec + 688128;              // 768000
  double* kinv = (double*)(keyn + 768000);  // 1000 doubles (2048 floats)
  float* xq    = keyn + 768000 + 2048;      // 344064
  float* of    = xq + 344064;               // 129024
  float* h     = of + 129024;               // 23396352 f (30464 x 768)
  ushort* abuf16 = (ushort*)(h + 23396352); // 23396352 us (30464 x 768)
  ushort* scr16  = abuf16 + 23396352;       // 13369344 us (4352 x 3072 max)
  ushort* w16    = scr16 + 13369344;        // 7077888 us (per-layer weights)
  ushort* owT16  = w16 + 7077888;           // 1671168 us (96 x 17408)

  ushort* wqT  = w16;                          // 2304 x 768
  ushort* waT  = wqT + 2304 * 768;             // 768 x 768
  ushort* wfcT = waT + 768 * 768;              // 3072 x 768
  ushort* wmpT = wfcT + 3072 * 768;            // 768 x 3072

  revin_kernel<<<448, 256, 0, stream>>>(x, xr, means, stdev);
  decompose_kernel<<<448, 256, 0, stream>>>(xr, dec);
  embed_kernel<<<NEMB, 256, 0, stream>>>(dec, in_w, in_b, h);
  keyn_kernel<<<1000, 256, 0, stream>>>(pkey, keyn, kinv);
  xq_kernel<<<448, 256, 0, stream>>>(h, xq);
  zero_kernel<<<1, 64, 0, stream>>>(out + 43008);
  simtopk_kernel<<<448, 256, 0, stream>>>(xq, pkey, kinv, keyn, wpe, h, out + 43008);
  addwpe_kernel<<<NEMB, 256, 0, stream>>>(wpe, h);

  for (int l = 0; l < 6; l++) {
    tcast_kernel<<<dim3(72, 24), 256, 0, stream>>>(qkv_w + (size_t)l * 768 * 2304, wqT, 768, 2304);
    tcast_kernel<<<dim3(24, 24), 256, 0, stream>>>(aw    + (size_t)l * 768 * 768,  waT, 768, 768);
    tcast_kernel<<<dim3(96, 24), 256, 0, stream>>>(fc_w  + (size_t)l * 768 * 3072, wfcT, 768, 3072);
    tcast_kernel<<<dim3(24, 96), 256, 0, stream>>>(mp_w  + (size_t)l * 3072 * 768, wmpT, 3072, 768);

    ln_kernel<<<NTOK, 256, 0, stream>>>(h, abuf16, ln1_g + l * 768, ln1_b + l * 768);
    for (int c = 0; c < NCH; c++) {
      mfma_gemm<<<dim3(18, 34), 256, 0, stream>>>(
          abuf16 + (size_t)c * RCH * 768, wqT, qkv_b + l * 2304, scr16,
          RCH, 2304, 768, 0);
      attn_kernel<<<SCH * 12, 256, 0, stream>>>(scr16, abuf16 + (size_t)c * RCH * 768);
    }
    mfma_gemm<<<dim3(6, 238), 256, 0, stream>>>(
        abuf16, waT, ab + l * 768, h, NTOK, 768, 768, 2);
    ln_kernel<<<NTOK, 256, 0, stream>>>(h, abuf16, ln2_g + l * 768, ln2_b + l * 768);
    for (int c = 0; c < NCH; c++) {
      mfma_gemm<<<dim3(24, 34), 256, 0, stream>>>(
          abuf16 + (size_t)c * RCH * 768, wfcT, fc_b + l * 3072, scr16,
          RCH, 3072, 768, 1);
      mfma_gemm<<<dim3(6, 34), 256, 0, stream>>>(
          scr16, wmpT, mp_b + l * 768, h + (size_t)c * RCH * 768,
          RCH, 768, 3072, 2);
    }
  }
  ln_kernel<<<NTOK, 256, 0, stream>>>(h, abuf16, lnf_g, lnf_b);
  tcast_kernel<<<dim3(3, 544), 256, 0, stream>>>(out_w, owT16, 17408, 96);
  initof_kernel<<<504, 256, 0, stream>>>(out_b, of);
  splitk_kernel<<<dim3(21, 17), 256, 0, stream>>>(abuf16, owT16, of);
  combine_kernel<<<448, 96, 0, stream>>>(of, stdev, means, out);
}

// Round 5
// 7531.355 us; speedup vs baseline: 6.9879x; 1.4392x over previous
//
#include <hip/hip_runtime.h>
#include <math.h>

// ---------------- constants ----------------
#define NTOK 30464    // 448*68 = 238 tiles of 128
#define NEMB 28672    // 448*64
typedef unsigned short ushort;
typedef __attribute__((ext_vector_type(8))) __bf16 bf16x8_t;
typedef __attribute__((ext_vector_type(4))) float f32x4_t;

#if defined(__has_builtin)
#if __has_builtin(__builtin_amdgcn_global_load_lds)
#define HAS_GLL 1
#endif
#endif

// ---------------- helpers ----------------
__device__ __forceinline__ ushort f2bf(float f) {
  unsigned int u = __float_as_uint(f);
  u += 0x7fffu + ((u >> 16) & 1u);   // RNE (finite inputs)
  return (ushort)(u >> 16);
}
__device__ __forceinline__ float bf2f(ushort u) {
  return __uint_as_float(((unsigned int)u) << 16);
}

#ifdef HAS_GLL
__device__ __forceinline__ void gll16(const ushort* g, ushort* l) {
  __builtin_amdgcn_global_load_lds(
      (const __attribute__((address_space(1))) unsigned int*)g,
      (__attribute__((address_space(3))) unsigned int*)l, 16, 0, 0);
}
#endif

__device__ __forceinline__ float block_reduce_sum(float v, float* scratch) {
  __syncthreads();
  #pragma unroll
  for (int o = 32; o; o >>= 1) v += __shfl_xor(v, o, 64);
  int wid = threadIdx.x >> 6, lane = threadIdx.x & 63;
  if (lane == 0) scratch[wid] = v;
  __syncthreads();
  if (threadIdx.x == 0) {
    float s = 0.f;
    int nw = (blockDim.x + 63) >> 6;
    for (int i = 0; i < nw; i++) s += scratch[i];
    scratch[0] = s;
  }
  __syncthreads();
  return scratch[0];
}

// exact tanh-gelu via sigmoid identity: 0.5x(1+tanh(z)) = x / (1 + e^{-2z})
__device__ __forceinline__ float gelu_f(float x) {
  float z2 = 1.5957691216057308f * (x + 0.044715f * x * x * x);
  return x / (1.0f + __expf(-z2));
}

// ---------------- RevIN ----------------
__global__ __launch_bounds__(256) void revin_kernel(const float* __restrict__ x,
    float* __restrict__ xr, float* __restrict__ means, float* __restrict__ stdev) {
  int bm = blockIdx.x;
  int b = bm / 7, m = bm % 7;
  int tid = threadIdx.x;
  __shared__ float red[8];
  float v0 = x[(size_t)b * 3584 + (size_t)tid * 7 + m];
  float v1 = x[(size_t)b * 3584 + (size_t)(tid + 256) * 7 + m];
  float s  = block_reduce_sum(v0 + v1, red);
  float ss = block_reduce_sum(v0 * v0 + v1 * v1, red);
  float mean = s * (1.0f / 512.0f);
  float var  = ss * (1.0f / 512.0f) - mean * mean;
  float sd = sqrtf(var + 1e-5f);
  if (tid == 0) { means[bm] = mean; stdev[bm] = sd; }
  float inv = 1.0f / sd;
  xr[(size_t)bm * 512 + tid]       = (v0 - mean) * inv;
  xr[(size_t)bm * 512 + tid + 256] = (v1 - mean) * inv;
}

// ---------------- decompose ----------------
__global__ __launch_bounds__(256) void decompose_kernel(const float* __restrict__ xr,
    float* __restrict__ dec) {
  int n = blockIdx.x, tid = threadIdx.x;
  __shared__ float xv[512];
  __shared__ float tr[512];
  __shared__ float sumS[24];
  for (int l = tid; l < 512; l += 256) xv[l] = xr[(size_t)n * 512 + l];
  if (tid < 24) sumS[tid] = 0.f;
  __syncthreads();
  for (int l = tid; l < 512; l += 256) {
    int t0 = l - 12; t0 = t0 < 0 ? 0 : (t0 > 488 ? 488 : t0);
    float s = 0.f;
    #pragma unroll
    for (int j = 0; j < 24; j++) s += xv[t0 + j];
    float t = s * (1.0f / 24.0f);
    tr[l] = t;
    atomicAdd(&sumS[l % 24], xv[l] - t);
  }
  __syncthreads();
  if (tid < 24) sumS[tid] *= (tid < 8) ? (1.0f / 22.0f) : (1.0f / 21.0f);
  __syncthreads();
  float* dp = dec + (size_t)n * 1536;
  for (int l = tid; l < 512; l += 256) {
    float t = tr[l], se = sumS[l % 24];
    dp[l] = t;
    dp[512 + l] = se;
    dp[1024 + l] = xv[l] - t - se;
  }
}

// ---------------- patch + embed -> h rows 4..67 (NO wpe yet) ----------------
__global__ __launch_bounds__(256) void embed_kernel(const float* __restrict__ dec,
    const float* __restrict__ in_w, const float* __restrict__ in_b, float* __restrict__ h) {
  int np = blockIdx.x;
  int n = np >> 6, p = np & 63;
  int tid = threadIdx.x;
  __shared__ float tok[48];
  if (tid < 48) {
    int c = tid >> 4, j = tid & 15;
    int l = p * 8 + j; if (l > 511) l = 511;
    tok[tid] = dec[(size_t)n * 1536 + (size_t)c * 512 + l];
  }
  __syncthreads();
  float* outp = h + ((size_t)n * 68 + 4 + p) * 768;
  #pragma unroll
  for (int i = 0; i < 3; i++) {
    int d = tid + i * 256;
    float acc = in_b[d];
    #pragma unroll
    for (int k = 0; k < 48; k++) acc += tok[k] * in_w[(size_t)k * 768 + d];
    outp[d] = acc;
  }
}

// ---------------- key normalization ----------------
__global__ __launch_bounds__(256) void keyn_kernel(const float* __restrict__ pkey,
    float* __restrict__ keyn, double* __restrict__ kinv) {
  int k = blockIdx.x, tid = threadIdx.x;
  __shared__ double redd[4];
  float v[3];
  double ss = 0.0;
  #pragma unroll
  for (int i = 0; i < 3; i++) {
    v[i] = pkey[(size_t)k * 768 + tid + i * 256];
    ss += (double)v[i] * (double)v[i];
  }
  #pragma unroll
  for (int o = 32; o; o >>= 1) ss += __shfl_xor(ss, o, 64);
  int wid = tid >> 6, lane = tid & 63;
  if (lane == 0) redd[wid] = ss;
  __syncthreads();
  if (tid == 0) redd[0] = redd[0] + redd[1] + redd[2] + redd[3];
  __syncthreads();
  ss = redd[0];
  double inv = 1.0 / sqrt(ss > 1e-12 ? ss : 1e-12);
  #pragma unroll
  for (int i = 0; i < 3; i++)
    keyn[(size_t)k * 768 + tid + i * 256] = (float)((double)v[i] * inv);
  if (tid == 0) kinv[k] = inv;
}

// ---------------- xq ----------------
__global__ __launch_bounds__(256) void xq_kernel(const float* __restrict__ h,
    float* __restrict__ xq) {
  int n = blockIdx.x, tid = threadIdx.x;
  __shared__ float red[8];
  float vals[3];
  float ssl = 0.f;
  #pragma unroll
  for (int i = 0; i < 3; i++) {
    int d = tid + i * 256;
    const float* p = h + ((size_t)n * 68 + 4) * 768 + d;
    float s = 0.f;
    for (int pc = 0; pc < 64; pc++) s += p[(size_t)pc * 768];
    s *= (1.0f / 64.0f);
    vals[i] = s; ssl += s * s;
  }
  float ss = block_reduce_sum(ssl, red);
  float inv = rsqrtf(fmaxf(ss, 1e-12f));
  #pragma unroll
  for (int i = 0; i < 3; i++)
    xq[(size_t)n * 768 + tid + i * 256] = vals[i] * inv;
}

__global__ void zero_kernel(float* p) {
  if (threadIdx.x == 0 && blockIdx.x == 0) p[0] = 0.f;
}

// ---------------- sim (f64, 4-key ILP) + top-4 + prompt rows + reduce_sim ----------------
__global__ __launch_bounds__(256) void simtopk_kernel(
    const float* __restrict__ xq, const float* __restrict__ pkey,
    const double* __restrict__ kinv, const float* __restrict__ keyn,
    const float* __restrict__ wpe, float* __restrict__ h, float* __restrict__ rs_out) {
  int n = blockIdx.x, tid = threadIdx.x;
  __shared__ __align__(16) float xqv[768];
  __shared__ double simd_s[1000];
  __shared__ int idxs[4];
  __shared__ double redv[4];
  __shared__ int redi[4];
  __shared__ float red2[8];
  #pragma unroll
  for (int i = 0; i < 3; i++) xqv[tid + i * 256] = xq[(size_t)n * 768 + tid + i * 256];
  __syncthreads();
  int lane = tid & 63, wid = tid >> 6;
  // wave handles 4 consecutive keys per iteration (independent f64 chains)
  for (int k4 = wid * 4; k4 < 1000; k4 += 16) {
    double a[4] = {0.0, 0.0, 0.0, 0.0};
    #pragma unroll
    for (int i = 0; i < 12; i++) {
      int d = lane + 64 * i;
      double xv = (double)xqv[d];
      #pragma unroll
      for (int t = 0; t < 4; t++)
        a[t] += (double)pkey[(size_t)(k4 + t) * 768 + d] * xv;
    }
    #pragma unroll
    for (int t = 0; t < 4; t++)
      #pragma unroll
      for (int o = 32; o; o >>= 1) a[t] += __shfl_xor(a[t], o, 64);
    if (lane == 0) {
      #pragma unroll
      for (int t = 0; t < 4; t++) simd_s[k4 + t] = a[t] * kinv[k4 + t];
    }
  }
  __syncthreads();
  for (int r = 0; r < 4; r++) {
    double bv = -1e300; int bi = 0x7fffffff;
    for (int k = tid; k < 1000; k += 256) {
      double v = simd_s[k];
      if (v > bv || (v == bv && k < bi)) { bv = v; bi = k; }
    }
    #pragma unroll
    for (int off = 32; off; off >>= 1) {
      double ov = __shfl_xor(bv, off, 64);
      int oi = __shfl_xor(bi, off, 64);
      if (ov > bv || (ov == bv && oi < bi)) { bv = ov; bi = oi; }
    }
    if (lane == 0) { redv[wid] = bv; redi[wid] = bi; }
    __syncthreads();
    if (tid == 0) {
      double fv = redv[0]; int fi = redi[0];
      for (int w = 1; w < 4; w++)
        if (redv[w] > fv || (redv[w] == fv && redi[w] < fi)) { fv = redv[w]; fi = redi[w]; }
      idxs[r] = fi; simd_s[fi] = -1e300;
    }
    __syncthreads();
  }
  float part = 0.f;
  for (int r = 0; r < 4; r++) {
    int ki = idxs[r];
    const float* kp = keyn + (size_t)ki * 768;
    const float* wp = wpe + (size_t)r * 768;
    float* hp = h + ((size_t)n * 68 + r) * 768;
    #pragma unroll
    for (int i = 0; i < 3; i++) {
      int d = tid + i * 256;
      float kv = kp[d];
      hp[d] = kv + wp[d];
      part += kv * xqv[d];
    }
  }
  part = block_reduce_sum(part, red2);
  if (tid == 0) atomicAdd(rs_out, part * (1.0f / 448.0f));
}

// ---------------- h rows 4..67 += wpe ----------------
__global__ __launch_bounds__(256) void addwpe_kernel(const float* __restrict__ wpe,
    float* __restrict__ h) {
  int np = blockIdx.x;
  int n = np >> 6, p = np & 63;
  int tid = threadIdx.x;
  const float* wp = wpe + (size_t)(4 + p) * 768;
  float* hp = h + ((size_t)n * 68 + 4 + p) * 768;
  #pragma unroll
  for (int i = 0; i < 3; i++) { int d = tid + i * 256; hp[d] += wp[d]; }
}

// ---------------- LayerNorm -> bf16 ----------------
__global__ __launch_bounds__(256) void ln_kernel(const float* __restrict__ src,
    ushort* __restrict__ dst, const float* __restrict__ g, const float* __restrict__ b) {
  size_t row = blockIdx.x;
  const float* xp = src + row * 768;
  ushort* yp = dst + row * 768;
  int tid = threadIdx.x;
  float v0 = xp[tid], v1 = xp[tid + 256], v2 = xp[tid + 512];
  __shared__ float red[8];
  float s  = block_reduce_sum(v0 + v1 + v2, red);
  float ss = block_reduce_sum(v0 * v0 + v1 * v1 + v2 * v2, red);
  float mean = s * (1.0f / 768.0f);
  float var  = ss * (1.0f / 768.0f) - mean * mean;
  float rs = rsqrtf(var + 1e-5f);
  yp[tid]       = f2bf((v0 - mean) * rs * g[tid]       + b[tid]);
  yp[tid + 256] = f2bf((v1 - mean) * rs * g[tid + 256] + b[tid + 256]);
  yp[tid + 512] = f2bf((v2 - mean) * rs * g[tid + 512] + b[tid + 512]);
}

// ---------------- cast+transpose weights: W[K][N] f32 -> WT[N][K] bf16 ----------------
__global__ __launch_bounds__(256) void tcast_kernel(const float* __restrict__ W,
    ushort* __restrict__ WT, int K, int N) {
  __shared__ ushort t[32][33];
  int n0 = blockIdx.x * 32, k0 = blockIdx.y * 32;
  int tx = threadIdx.x & 31, ty = threadIdx.x >> 5;   // 32 x 8
  #pragma unroll
  for (int i = 0; i < 4; i++) {
    int kk = ty + i * 8;
    t[kk][tx] = f2bf(W[(size_t)(k0 + kk) * N + n0 + tx]);
  }
  __syncthreads();
  #pragma unroll
  for (int i = 0; i < 4; i++) {
    int nn = ty + i * 8;
    WT[(size_t)(n0 + nn) * K + k0 + tx] = t[tx][nn];
  }
}

// ---------------- bf16 MFMA GEMM (m97-style global_load_lds staging) ----------------
// C = A(MxK) @ WT(NxK)^T + bias. 128x128 tile, 4 waves, 16x16x32 bf16.
// mode 0: C bf16;  1: C bf16 w/ gelu;  2: C fp32 += (residual)
__global__ __launch_bounds__(256) void mfma_gemm(const ushort* __restrict__ A,
    const ushort* __restrict__ WT, const float* __restrict__ bias, void* __restrict__ Cp,
    int M, int N, int K, int mode) {
  __shared__ ushort As[128 * 32];
  __shared__ ushort Bs[128 * 32];
  const int tid = threadIdx.x;
  const int row0 = blockIdx.y * 128, col0 = blockIdx.x * 128;
  const int w = tid >> 6, lane = tid & 63;
  const int wm = w >> 1, wn = w & 1;
  const int lm = lane & 15, quad = lane >> 4;
  const int srow = w * 16 + (lane >> 2);
  const int scol = (lane & 3) * 8;
  const ushort* agp0 = A  + (size_t)(row0 + srow)      * K + scol;
  const ushort* agp1 = A  + (size_t)(row0 + 64 + srow) * K + scol;
  const ushort* bgp0 = WT + (size_t)(col0 + srow)      * K + scol;
  const ushort* bgp1 = WT + (size_t)(col0 + 64 + srow) * K + scol;
  ushort* al0 = &As[w * 512];
  ushort* al1 = &As[2048 + w * 512];
  ushort* bl0 = &Bs[w * 512];
  ushort* bl1 = &Bs[2048 + w * 512];
  f32x4_t acc[4][4];
  #pragma unroll
  for (int mi = 0; mi < 4; mi++)
    #pragma unroll
    for (int ni = 0; ni < 4; ni++) acc[mi][ni] = (f32x4_t)(0.0f);

  for (int kb = 0; kb < K; kb += 32) {
    __syncthreads();
#ifdef HAS_GLL
    gll16(agp0 + kb, al0);
    gll16(agp1 + kb, al1);
    gll16(bgp0 + kb, bl0);
    gll16(bgp1 + kb, bl1);
#else
    {
      uint4 va0 = *(const uint4*)(agp0 + kb);
      uint4 va1 = *(const uint4*)(agp1 + kb);
      uint4 vb0 = *(const uint4*)(bgp0 + kb);
      uint4 vb1 = *(const uint4*)(bgp1 + kb);
      *(uint4*)&al0[lane * 8] = va0;
      *(uint4*)&al1[lane * 8] = va1;
      *(uint4*)&bl0[lane * 8] = vb0;
      *(uint4*)&bl1[lane * 8] = vb1;
    }
#endif
    __syncthreads();
    bf16x8_t af[4], bfr[4];
    #pragma unroll
    for (int mi = 0; mi < 4; mi++)
      af[mi] = *(const bf16x8_t*)&As[(wm * 64 + mi * 16 + lm) * 32 + quad * 8];
    #pragma unroll
    for (int ni = 0; ni < 4; ni++)
      bfr[ni] = *(const bf16x8_t*)&Bs[(wn * 64 + ni * 16 + lm) * 32 + quad * 8];
    #pragma unroll
    for (int mi = 0; mi < 4; mi++)
      #pragma unroll
      for (int ni = 0; ni < 4; ni++)
        acc[mi][ni] = __builtin_amdgcn_mfma_f32_16x16x32_bf16(af[mi], bfr[ni], acc[mi][ni], 0, 0, 0);
  }
  #pragma unroll
  for (int mi = 0; mi < 4; mi++) {
    #pragma unroll
    for (int ni = 0; ni < 4; ni++) {
      int gcol = col0 + wn * 64 + ni * 16 + lm;
      float bz = bias[gcol];
      #pragma unroll
      for (int r = 0; r < 4; r++) {
        int grow = row0 + wm * 64 + mi * 16 + quad * 4 + r;
        float v = acc[mi][ni][r] + bz;
        if (mode == 0)      ((ushort*)Cp)[(size_t)grow * N + gcol] = f2bf(v);
        else if (mode == 1) ((ushort*)Cp)[(size_t)grow * N + gcol] = f2bf(gelu_f(v));
        else { float* c = (float*)Cp + (size_t)grow * N + gcol; *c += v; }
      }
    }
  }
}

// ---------------- MFMA attention: block = (series-in-chunk, head) ----------------
__global__ __launch_bounds__(256) void attn_kernel(const ushort* __restrict__ qkvc,
    ushort* __restrict__ obase) {
  __shared__ __align__(16) ushort qk[2 * 80 * 64];
  __shared__ __align__(16) ushort vt[64][96];
  __shared__ __align__(16) float  sS[68][80];
  ushort* qs = qk;
  ushort* ks = qk + 80 * 64;
  ushort (*P)[96] = (ushort(*)[96])qk;

  int nh = blockIdx.x;
  int nl = nh / 12, hh = nh % 12;
  int tid = threadIdx.x;
  const int w = tid >> 6, lane = tid & 63;
  const int lm = lane & 15, quad = lane >> 4;
  const ushort* base = qkvc + (size_t)nl * 68 * 2304 + hh * 64;

  for (int idx = tid; idx < 68 * 64; idx += 256) {
    int t = idx >> 6, d = idx & 63;
    const ushort* rp = base + (size_t)t * 2304 + d;
    qs[t * 64 + d] = rp[0];
    ks[t * 64 + d] = rp[768];
    vt[d][t] = rp[1536];
  }
  for (int idx = tid; idx < 64 * 28; idx += 256) {
    int d = idx / 28, t = 68 + idx % 28;
    vt[d][t] = 0;
  }
  __syncthreads();

  for (int t5 = w; t5 < 25; t5 += 4) {
    int mi = t5 / 5, ni = t5 % 5;
    bf16x8_t a0 = *(const bf16x8_t*)&qs[(mi * 16 + lm) * 64 + quad * 8];
    bf16x8_t a1 = *(const bf16x8_t*)&qs[(mi * 16 + lm) * 64 + 32 + quad * 8];
    bf16x8_t b0 = *(const bf16x8_t*)&ks[(ni * 16 + lm) * 64 + quad * 8];
    bf16x8_t b1 = *(const bf16x8_t*)&ks[(ni * 16 + lm) * 64 + 32 + quad * 8];
    f32x4_t acc = (f32x4_t)(0.0f);
    acc = __builtin_amdgcn_mfma_f32_16x16x32_bf16(a0, b0, acc, 0, 0, 0);
    acc = __builtin_amdgcn_mfma_f32_16x16x32_bf16(a1, b1, acc, 0, 0, 0);
    int col = ni * 16 + lm;
    #pragma unroll
    for (int r = 0; r < 4; r++) {
      int row = mi * 16 + quad * 4 + r;
      if (row < 68) {
        float sv = (col > row || col >= 68) ? -1e9f : acc[r] * 0.125f;
        sS[row][col] = sv;
      }
    }
  }
  __syncthreads();

  if (tid < 68) {
    int r = tid;
    float mx = -1e30f;
    for (int c = 0; c < 80; c++) mx = fmaxf(mx, sS[r][c]);
    float sum = 0.f;
    for (int c = 0; c < 80; c++) { float e = __expf(sS[r][c] - mx); sS[r][c] = e; sum += e; }
    float inv = 1.0f / sum;
    for (int c = 0; c < 80; c++) P[r][c] = f2bf(sS[r][c] * inv);
    #pragma unroll
    for (int c = 80; c < 96; c++) P[r][c] = 0;
  } else if (tid < 80) {
    for (int c = 0; c < 96; c++) P[tid][c] = 0;
  }
  __syncthreads();

  for (int t5 = w; t5 < 20; t5 += 4) {
    int mi = t5 % 5, ni = t5 / 5;
    f32x4_t acc = (f32x4_t)(0.0f);
    #pragma unroll
    for (int kk = 0; kk < 3; kk++) {
      bf16x8_t a = *(const bf16x8_t*)&P[mi * 16 + lm][kk * 32 + quad * 8];
      bf16x8_t b = *(const bf16x8_t*)&vt[ni * 16 + lm][kk * 32 + quad * 8];
      acc = __builtin_amdgcn_mfma_f32_16x16x32_bf16(a, b, acc, 0, 0, 0);
    }
    int col = ni * 16 + lm;
    #pragma unroll
    for (int r = 0; r < 4; r++) {
      int row = mi * 16 + quad * 4 + r;
      if (row < 68)
        obase[((size_t)nl * 68 + row) * 768 + hh * 64 + col] = f2bf(acc[r]);
    }
  }
}

// ---------------- final head ----------------
__global__ __launch_bounds__(256) void initof_kernel(const float* __restrict__ ob,
    float* __restrict__ of) {
  int i = blockIdx.x * 256 + threadIdx.x;
  of[i] = ob[i % 96];
}

__global__ __launch_bounds__(256) void splitk_kernel(const ushort* __restrict__ A,
    const ushort* __restrict__ WT, float* __restrict__ of) {
  __shared__ ushort As[64][40];
  __shared__ ushort Ws[96][40];
  int row0 = blockIdx.x * 64;
  int k0 = blockIdx.y * 1024;
  int tid = threadIdx.x;
  int tx = tid & 15, ty = tid >> 4;
  float acc[4][6] = {};
  for (int kb = k0; kb < k0 + 1024; kb += 32) {
    __syncthreads();
    {
      int m = tid >> 2, seg = (tid & 3) * 8;
      uint4 v = *(const uint4*)(A + (size_t)(row0 + m) * 17408 + kb + seg);
      *(uint4*)&As[m][seg] = v;
    }
    for (int idx = tid; idx < 384; idx += 256) {
      int n = idx >> 2, seg = (idx & 3) * 8;
      uint4 v = *(const uint4*)(WT + (size_t)n * 17408 + kb + seg);
      *(uint4*)&Ws[n][seg] = v;
    }
    __syncthreads();
    for (int k = 0; k < 32; k++) {
      float av[4], wv[6];
      #pragma unroll
      for (int i = 0; i < 4; i++) av[i] = bf2f(As[ty * 4 + i][k]);
      #pragma unroll
      for (int j = 0; j < 6; j++) wv[j] = bf2f(Ws[tx * 6 + j][k]);
      #pragma unroll
      for (int i = 0; i < 4; i++)
        #pragma unroll
        for (int j = 0; j < 6; j++) acc[i][j] += av[i] * wv[j];
    }
  }
  #pragma unroll
  for (int i = 0; i < 4; i++)
    #pragma unroll
    for (int j = 0; j < 6; j++)
      atomicAdd(&of[(size_t)(row0 + ty * 4 + i) * 96 + tx * 6 + j], acc[i][j]);
}

__global__ void combine_kernel(const float* __restrict__ of, const float* __restrict__ stdev,
    const float* __restrict__ means, float* __restrict__ out) {
  int bm = blockIdx.x;
  int b = bm / 7, m = bm % 7;
  int j = threadIdx.x;
  if (j < 96) {
    float s = of[(size_t)(bm * 3 + 0) * 96 + j]
            + of[(size_t)(bm * 3 + 1) * 96 + j]
            + of[(size_t)(bm * 3 + 2) * 96 + j];
    out[(size_t)b * 672 + (size_t)j * 7 + m] = s * stdev[bm] + means[bm];
  }
}

// ---------------- launcher ----------------
extern "C" void kernel_launch(void* const* d_in, const int* in_sizes, int n_in,
                              void* d_out, int out_size, void* d_ws, size_t ws_size,
                              hipStream_t stream) {
  (void)in_sizes; (void)n_in; (void)out_size;
  const float* x     = (const float*)d_in[0];
  const float* in_w  = (const float*)d_in[2];
  const float* in_b  = (const float*)d_in[3];
  const float* pkey  = (const float*)d_in[4];
  const float* wpe   = (const float*)d_in[5];
  const float* ln1_g = (const float*)d_in[6];
  const float* ln1_b = (const float*)d_in[7];
  const float* qkv_w = (const float*)d_in[8];
  const float* qkv_b = (const float*)d_in[9];
  const float* aw    = (const float*)d_in[10];
  const float* ab    = (const float*)d_in[11];
  const float* ln2_g = (const float*)d_in[12];
  const float* ln2_b = (const float*)d_in[13];
  const float* fc_w  = (const float*)d_in[14];
  const float* fc_b  = (const float*)d_in[15];
  const float* mp_w  = (const float*)d_in[16];
  const float* mp_b  = (const float*)d_in[17];
  const float* lnf_g = (const float*)d_in[18];
  const float* lnf_b = (const float*)d_in[19];
  const float* out_w = (const float*)d_in[20];
  const float* out_b = (const float*)d_in[21];
  float* out = (float*)d_out;
  float* ws  = (float*)d_ws;

  // workspace layout: small (2,161,664 f) + h + abuf16 + w16 + scr (rest)
  float* means = ws;
  float* stdev = ws + 512;
  float* xr    = ws + 1024;
  float* dec   = xr + 229376;
  float* keyn  = dec + 688128;
  double* kinv = (double*)(keyn + 768000);
  float* xq    = keyn + 768000 + 2048;
  float* of    = xq + 344064;
  float* h     = of + 129024;                 // 23,396,352 f
  ushort* abuf16 = (ushort*)(h + 23396352);   // 23,396,352 us
  ushort* w16    = abuf16 + 23396352;         // 7,077,888 us
  ushort* scr16  = w16 + 7077888;             // remainder
  ushort* owT16  = scr16;                     // alias (only used after layers)

  ushort* wqT  = w16;                         // 2304 x 768
  ushort* waT  = wqT + 2304 * 768;            // 768 x 768
  ushort* wfcT = waT + 768 * 768;             // 3072 x 768
  ushort* wmpT = wfcT + 3072 * 768;           // 768 x 3072

  // dynamic chunking from ws_size (constant across calls -> graph-safe)
  size_t scr_bytes = ws_size - (size_t)((char*)scr16 - (char*)ws);
  // qkv chunks: units of 17 tiles (= 2176 rows = 32 series), 14 units total
  long cap_qg = (long)(scr_bytes / (17ull * 128 * 2304 * 2));
  if (cap_qg > 14) cap_qg = 14;
  if (cap_qg < 1) cap_qg = 1;
  int nch_q = (int)((14 + cap_qg - 1) / cap_qg);
  int gpc = (14 + nch_q - 1) / nch_q;         // 17-tile groups per chunk
  // fc chunks: units of 1 tile (128 rows), 238 tiles total
  long cap_ft = (long)(scr_bytes / (128ull * 3072 * 2));
  if (cap_ft > 238) cap_ft = 238;
  if (cap_ft < 1) cap_ft = 1;
  int nch_f = (int)((238 + cap_ft - 1) / cap_ft);
  int tpc = (238 + nch_f - 1) / nch_f;        // tiles per chunk

  revin_kernel<<<448, 256, 0, stream>>>(x, xr, means, stdev);
  decompose_kernel<<<448, 256, 0, stream>>>(xr, dec);
  embed_kernel<<<NEMB, 256, 0, stream>>>(dec, in_w, in_b, h);
  keyn_kernel<<<1000, 256, 0, stream>>>(pkey, keyn, kinv);
  xq_kernel<<<448, 256, 0, stream>>>(h, xq);
  zero_kernel<<<1, 64, 0, stream>>>(out + 43008);
  simtopk_kernel<<<448, 256, 0, stream>>>(xq, pkey, kinv, keyn, wpe, h, out + 43008);
  addwpe_kernel<<<NEMB, 256, 0, stream>>>(wpe, h);

  for (int l = 0; l < 6; l++) {
    tcast_kernel<<<dim3(72, 24), 256, 0, stream>>>(qkv_w + (size_t)l * 768 * 2304, wqT, 768, 2304);
    tcast_kernel<<<dim3(24, 24), 256, 0, stream>>>(aw    + (size_t)l * 768 * 768,  waT, 768, 768);
    tcast_kernel<<<dim3(96, 24), 256, 0, stream>>>(fc_w  + (size_t)l * 768 * 3072, wfcT, 768, 3072);
    tcast_kernel<<<dim3(24, 96), 256, 0, stream>>>(mp_w  + (size_t)l * 3072 * 768, wmpT, 3072, 768);

    ln_kernel<<<NTOK, 256, 0, stream>>>(h, abuf16, ln1_g + l * 768, ln1_b + l * 768);
    for (int g0 = 0; g0 < 14; ) {
      int g = (gpc < 14 - g0) ? gpc : (14 - g0);
      int tiles = g * 17, rows = g * 2176, series = g * 32;
      ushort* Ain = abuf16 + (size_t)g0 * 2176 * 768;
      mfma_gemm<<<dim3(18, tiles), 256, 0, stream>>>(
          Ain, wqT, qkv_b + l * 2304, scr16, rows, 2304, 768, 0);
      attn_kernel<<<series * 12, 256, 0, stream>>>(scr16, Ain);
      g0 += g;
    }
    mfma_gemm<<<dim3(6, 238), 256, 0, stream>>>(
        abuf16, waT, ab + l * 768, h, NTOK, 768, 768, 2);
    ln_kernel<<<NTOK, 256, 0, stream>>>(h, abuf16, ln2_g + l * 768, ln2_b + l * 768);
    for (int t0 = 0; t0 < 238; ) {
      int t = (tpc < 238 - t0) ? tpc : (238 - t0);
      mfma_gemm<<<dim3(24, t), 256, 0, stream>>>(
          abuf16 + (size_t)t0 * 128 * 768, wfcT, fc_b + l * 3072, scr16,
          t * 128, 3072, 768, 1);
      mfma_gemm<<<dim3(6, t), 256, 0, stream>>>(
          scr16, wmpT, mp_b + l * 768, h + (size_t)t0 * 128 * 768,
          t * 128, 768, 3072, 2);
      t0 += t;
    }
  }
  ln_kernel<<<NTOK, 256, 0, stream>>>(h, abuf16, lnf_g, lnf_b);
  tcast_kernel<<<dim3(3, 544), 256, 0, stream>>>(out_w, owT16, 17408, 96);
  initof_kernel<<<504, 256, 0, stream>>>(out_b, of);
  splitk_kernel<<<dim3(21, 17), 256, 0, stream>>>(abuf16, owT16, of);
  combine_kernel<<<448, 96, 0, stream>>>(of, stdev, means, out);
}